// Round 7
// baseline (434.889 us; speedup 1.0000x reference)
//
#include <hip/hip_runtime.h>
#include <hip/hip_bf16.h>

// Swin window MHSA, MI355X, round 13.
//   k_prep : Aext[2176x256]=G'(+w1/w2 rows), Wov3[256x2048], cvec, relL2(+c0)
//   k_conv : X fp32 -> rolled bf16 Xroll  R13: register-row rewrite --
//            14x float4 loads + static-rotated unrolled stores (was 56x
//            {scalar 4B load + 2B store}; ~75us hidden cost found by
//            subtracting known kernels from totals).
//   k_fused: per (n,window): M=G'.X, S=Xp.M, softmax, T^T=X^T.w, out+=Wov3.T^T
//            R13: 1024 threads / 16 waves (launch_bounds(1024,4), VGPR<=128)
//            -> 4 waves/SIMD (R11/R12 ran 2/SIMD and were serialization-
//            bound: phase trimming moved nothing). Partitions re-cut for 16
//            waves with per-block LDS traffic ~flat; pays 2x L2 re-reads of
//            Aext/Wov3 (L2 at 16% has headroom). wfr in 2 chunks of [2][4]
//            to fit the 128-VGPR cap.

#define NBATCH 8
#define TROWS  3200           // padded token rows
#define FSTR   264            // LDS row stride for Xp/Msm/Tsm (bank-spread)

typedef unsigned short ushort_t;
typedef __attribute__((ext_vector_type(8))) short bf16x8;   // 8 bf16 = 4 VGPR
typedef __attribute__((ext_vector_type(8))) unsigned short u16x8;
typedef __attribute__((ext_vector_type(4))) float f32x4;    // MFMA acc

__device__ __forceinline__ float b2f(ushort_t u) {
  union { unsigned int i; float f; } v; v.i = ((unsigned int)u) << 16; return v.f;
}
__device__ __forceinline__ ushort_t f2b(float f) {
  union { float f; unsigned int u; } v; v.f = f;
  unsigned int u = v.u;
  return (ushort_t)((u + 0x7FFFu + ((u >> 16) & 1u)) >> 16);
}
__device__ __forceinline__ int regof(int y) { return (y < 49) ? 0 : ((y < 53) ? 1 : 2); }
__device__ __forceinline__ int div7(int t) { return (t * 37) >> 8; }  // t/7, t<64
__device__ __forceinline__ int tmap(int p, int gi, int gj) {
  int wi = div7(p); return (gi * 7 + wi) * 56 + gj * 7 + (p - wi * 7);
}
__device__ __forceinline__ ushort4 pack4(f32x4 a) {
  ushort4 u; u.x = f2b(a[0]); u.y = f2b(a[1]); u.z = f2b(a[2]); u.w = f2b(a[3]);
  return u;
}

// ================= prep (unchanged) =================
__global__ void k_prep(const float* __restrict__ Wk, const float* __restrict__ Wq,
                       const float* __restrict__ Wo, const float* __restrict__ Wv,
                       const float* __restrict__ bk, const float* __restrict__ bq,
                       const float* __restrict__ bv, const float* __restrict__ bo,
                       const float* __restrict__ relc,
                       ushort_t* __restrict__ Aext, ushort_t* __restrict__ Wov3,
                       float* __restrict__ cvec, float* __restrict__ relL2) {
  __shared__ float red[8];
  int blk = blockIdx.x, t = threadIdx.x;
  if (blk < 512) {
    int h = blk >> 6, b0 = (blk & 63) << 2, a = t;
    const float* wkh = Wk + h * 65536;
    const float* wqh = Wq + h * 65536;
    float a0 = 0.f, a1 = 0.f, a2 = 0.f, a3 = 0.f;
    for (int dd = 0; dd < 256; ++dd) {
      float wk = wkh[dd * 256 + a];
      float4 w4 = *(const float4*)(wqh + dd * 256 + b0);
      a0 += wk * w4.x; a1 += wk * w4.y; a2 += wk * w4.z; a3 += wk * w4.w;
    }
    ushort4 u; u.x = f2b(a0); u.y = f2b(a1); u.z = f2b(a2); u.w = f2b(a3);
    *(ushort4*)(Aext + (h * 256 + a) * 256 + b0) = u;
  } else if (blk < 1024) {
    int bb = blk - 512;
    int h = bb >> 6, o0 = (bb & 63) << 2, d = t;
    float a0 = 0.f, a1 = 0.f, a2 = 0.f, a3 = 0.f;
    for (int dd = 0; dd < 256; ++dd) {
      float wv = Wv[(h * 256 + dd) * 256 + d];
      a0 += Wo[(o0 + 0) * 2048 + h * 256 + dd] * wv;
      a1 += Wo[(o0 + 1) * 2048 + h * 256 + dd] * wv;
      a2 += Wo[(o0 + 2) * 2048 + h * 256 + dd] * wv;
      a3 += Wo[(o0 + 3) * 2048 + h * 256 + dd] * wv;
    }
    Wov3[(o0 + 0) * 2048 + h * 256 + d] = f2b(a0);
    Wov3[(o0 + 1) * 2048 + h * 256 + d] = f2b(a1);
    Wov3[(o0 + 2) * 2048 + h * 256 + d] = f2b(a2);
    Wov3[(o0 + 3) * 2048 + h * 256 + d] = f2b(a3);
  } else if (blk < 1032) {
    int h = blk - 1024;
    float s1 = 0.f, s2 = 0.f;
    for (int dd = 0; dd < 256; ++dd) {
      s1 += bk[h * 256 + dd] * Wq[(h * 256 + dd) * 256 + t];
      s2 += bq[h * 256 + dd] * Wk[(h * 256 + dd) * 256 + t];
    }
    Aext[(2048 + h) * 256 + t] = f2b(s1);
    Aext[(2056 + h) * 256 + t] = f2b(s2);
  } else if (blk == 1032) {
    for (int i = t; i < 112 * 256 / 8; i += 256)
      *(u16x8*)(Aext + 2064 * 256 + i * 8) = (u16x8){0,0,0,0,0,0,0,0};
  } else if (blk < 1289) {
    int o = blk - 1033;
    const float* wob = Wo + o * 2048;
    float acc = 0.f;
#pragma unroll
    for (int j = 0; j < 8; ++j) acc += wob[j * 256 + t] * bv[j * 256 + t];
#pragma unroll
    for (int s = 1; s < 64; s <<= 1) acc += __shfl_xor(acc, s);
    if ((t & 63) == 0) red[t >> 6] = acc;
    __syncthreads();
    if (t == 0) cvec[o] = bo[o] + red[0] + red[1] + red[2] + red[3];
  } else {
    if (t < 8) {
      float c = 0.f;
      for (int dd = 0; dd < 256; ++dd) c += bk[t * 256 + dd] * bq[t * 256 + dd];
      red[t] = c * 0.0625f;
    }
    __syncthreads();
    for (int i = t; i < 8 * 169; i += 256) {
      int h = i / 169, idx = i - h * 169;
      relL2[i] = relc[idx * 8 + h] + red[h];
    }
  }
}

// ================= conv: register-row, static-rotated stores ==============
__global__ void k_conv(const float* __restrict__ X, ushort_t* __restrict__ Xroll) {
  const int n = blockIdx.x / 57, y = blockIdx.x % 57;
  ushort_t* xr = Xroll + (size_t)n * TROWS * 256;
  const int d = threadIdx.x;
  if (y == 56) {  // zero pad rows 3136..3199
    for (int i = d; i < 64 * 256 / 8; i += 256)
      *(u16x8*)(xr + 3136 * 256 + i * 8) = (u16x8){0,0,0,0,0,0,0,0};
    return;
  }
  const int c = d >> 4, p1 = (d >> 2) & 3, p2 = d & 3;
  const int sp = c * 16 + (((p1 + 1) & 3) << 2) + ((p2 + 1) & 3);
  const int ty = (p1 == 3) ? y : ((y == 0) ? 55 : y - 1);
  const float* rowp = X + (size_t)n * 256 * 3136 + sp * 3136 + ty * 56;
  ushort_t* orow = xr + y * 56 * 256 + d;
  // load the whole 56-float row (16B-aligned: 3136 & 56 are /4)
  float row[56];
#pragma unroll
  for (int i = 0; i < 14; ++i) {
    const float4 t4 = ((const float4*)rowp)[i];
    row[i * 4 + 0] = t4.x; row[i * 4 + 1] = t4.y;
    row[i * 4 + 2] = t4.z; row[i * 4 + 3] = t4.w;
  }
  const bool nr = (p2 == 3);   // no roll along x for p2==3
#pragma unroll
  for (int x = 0; x < 56; ++x) {
    const float a = (x == 0) ? row[55] : row[x - 1];  // static indices
    orow[x * 256] = f2b(nr ? row[x] : a);   // 256 lanes -> 512B contiguous
  }
}

// ================= fused window attention (16 waves) ======================
// Block = (n = XCD via bx&7, window g = bx>>3). 1024 threads = 16 waves.
// Roles: S/softmax (wq=wave&3, wpt=wave>>2); m_step (wb=wave&7, th=wave>>3);
//        PV (qp=wave&1, dg=wave>>1); out (wo=wave&7, wq2=wave>>3).
__global__ __launch_bounds__(1024, 4) void k_fused(
    const ushort_t* __restrict__ Xroll, const ushort_t* __restrict__ Aext,
    const ushort_t* __restrict__ Wov3, const float* __restrict__ cvec,
    const float* __restrict__ relL2, float* __restrict__ out) {
  __shared__ ushort_t Xp[64 * FSTR];     // X window tokens [t][d]
  __shared__ ushort_t Msm[64 * FSTR];    // M_h [q][b-local]
  __shared__ ushort_t Tsm[64 * FSTR];    // T^T [q][d]
  __shared__ ushort_t StB[64 * 72];      // wmap [q][p]
  __shared__ float aqsL[8 * 64];
  __shared__ float bpsL[8 * 64];
  __shared__ float relLh[8 * 169];
  __shared__ float mPart[4][64];
  __shared__ float sPart[4][64];

  const int tid = threadIdx.x;
  const int wave = tid >> 6, lane = tid & 63;
  const int quad = lane >> 4, l16 = lane & 15;
  const int n = blockIdx.x & 7, g = blockIdx.x >> 3;
  const int gi = g >> 3, gj = g & 7;
  const ushort_t* Xn = Xroll + (size_t)n * TROWS * 256;
  float* on = out + (size_t)n * 256 * 3136;

  // ---- stage Xp (rows >=49 zeroed); 1024 threads: 16 cg x 2 chunks ----
  {
    const int p = tid & 63, cg = tid >> 6;
    if (p < 49) {
      int t = tmap(p, gi, gj);
#pragma unroll
      for (int i = 0; i < 2; ++i)
        *(u16x8*)(&Xp[p * FSTR + (cg * 2 + i) * 8]) =
            *(const u16x8*)(Xn + t * 256 + (cg * 2 + i) * 8);
    } else {
#pragma unroll
      for (int i = 0; i < 2; ++i)
        *(u16x8*)(&Xp[p * FSTR + (cg * 2 + i) * 8]) = (u16x8){0,0,0,0,0,0,0,0};
    }
  }
  for (int i = tid; i < 8 * 169; i += 1024) relLh[i] = relL2[i];
  __syncthreads();

  const int wq  = wave & 3,  wpt = wave >> 2;   // S/softmax role
  const int wb  = wave & 7,  th  = wave >> 3;   // m_step role
  const int qp  = wave & 1,  dg  = wave >> 1;   // PV role
  const int wo  = wave & 7,  wq2 = wave >> 3;   // out role

  // ---- xb: S-step Xp A-frags (p-tile wpt), invariant over h (32 VGPR) ----
  bf16x8 xb[8];
#pragma unroll
  for (int kk = 0; kk < 8; ++kk)
    xb[kk] = *(const bf16x8*)(&Xp[(wpt * 16 + l16) * FSTR + kk * 32 + quad * 8]);

  // ---- xfr: PV A-frags (X^T), d-tiles dg*2+{0,1} (16 VGPR) ----
  bf16x8 xfr[2][2];
#pragma unroll
  for (int dt = 0; dt < 2; ++dt) {
    const int dcol = (dg * 2 + dt) * 16 + l16;
#pragma unroll
    for (int kk = 0; kk < 2; ++kk)
#pragma unroll
      for (int j = 0; j < 8; ++j)
        xfr[dt][kk][j] = (short)Xp[(kk * 32 + quad * 8 + j) * FSTR + dcol];
  }

  // ---- m_step: M_h[t][b], 16 waves: 32 b-cols x 32 tokens each ----
  auto m_step = [&](int h) {
    f32x4 macc[2][2];
#pragma unroll
    for (int i = 0; i < 2; ++i)
#pragma unroll
      for (int t = 0; t < 2; ++t) macc[i][t] = (f32x4){0.f, 0.f, 0.f, 0.f};
    const ushort_t* Ah =
        Aext + (size_t)(h * 256 + wb * 32 + l16) * 256 + quad * 8;
#pragma unroll
    for (int kk = 0; kk < 8; ++kk) {
      bf16x8 ga[2];
#pragma unroll
      for (int i = 0; i < 2; ++i)
        ga[i] = *(const bf16x8*)(Ah + i * 16 * 256 + kk * 32);
#pragma unroll
      for (int t = 0; t < 2; ++t) {
        bf16x8 bx_ = *(const bf16x8*)(&Xp[(th * 32 + t * 16 + l16) * FSTR + kk * 32 + quad * 8]);
#pragma unroll
        for (int i = 0; i < 2; ++i)
          macc[i][t] = __builtin_amdgcn_mfma_f32_16x16x32_bf16(ga[i], bx_, macc[i][t], 0, 0, 0);
      }
    }
#pragma unroll
    for (int i = 0; i < 2; ++i)
#pragma unroll
      for (int t = 0; t < 2; ++t)
        *(ushort4*)(&Msm[(th * 32 + t * 16 + l16) * FSTR + wb * 32 + i * 16 + quad * 4]) =
            pack4(macc[i][t]);
  };

  m_step(0);
  if (wave == 0) {
    // Mext: rows 2048..2063 of Aext -> aqs (w1) / bps (w2) per token, f32
    f32x4 eacc[4];
#pragma unroll
    for (int t = 0; t < 4; ++t) eacc[t] = (f32x4){0.f, 0.f, 0.f, 0.f};
    const ushort_t* Ae = Aext + (size_t)(2048 + l16) * 256 + quad * 8;
#pragma unroll
    for (int kk = 0; kk < 8; ++kk) {
      bf16x8 ea = *(const bf16x8*)(Ae + kk * 32);
#pragma unroll
      for (int t = 0; t < 4; ++t) {
        bf16x8 bx_ = *(const bf16x8*)(&Xp[(t * 16 + l16) * FSTR + kk * 32 + quad * 8]);
        eacc[t] = __builtin_amdgcn_mfma_f32_16x16x32_bf16(ea, bx_, eacc[t], 0, 0, 0);
      }
    }
#pragma unroll
    for (int t = 0; t < 4; ++t) {
      const int tok = t * 16 + l16;
#pragma unroll
      for (int r = 0; r < 4; ++r) {
        const int e = quad * 4 + r;
        if (e < 8) aqsL[e * 64 + tok] = eacc[t][r];
        else       bpsL[(e - 8) * 64 + tok] = eacc[t][r];
      }
    }
  }
  __syncthreads();

  const int q = wq * 16 + l16;
  const int qq = (q < 49) ? q : 48;
  const int yq = div7(qq), xq = qq - yq * 7;
  const int fq = regof(gi * 7 + yq) * 3 + regof(gj * 7 + xq);

  f32x4 oacc[2][2];
#pragma unroll
  for (int i = 0; i < 2; ++i)
#pragma unroll
    for (int j = 0; j < 2; ++j) oacc[i][j] = (f32x4){0.f, 0.f, 0.f, 0.f};

  for (int h = 0; h < 8; ++h) {
    // ---- S-step: 16x16 tile (p-tile wpt x q-tile wq), dual chains ----
    f32x4 sa0 = (f32x4){0.f,0.f,0.f,0.f}, sa1 = (f32x4){0.f,0.f,0.f,0.f};
#pragma unroll
    for (int kk = 0; kk < 8; kk += 2) {
      bf16x8 bfm0 = *(const bf16x8*)(&Msm[q * FSTR + kk * 32 + quad * 8]);
      bf16x8 bfm1 = *(const bf16x8*)(&Msm[q * FSTR + (kk + 1) * 32 + quad * 8]);
      sa0 = __builtin_amdgcn_mfma_f32_16x16x32_bf16(xb[kk], bfm0, sa0, 0, 0, 0);
      sa1 = __builtin_amdgcn_mfma_f32_16x16x32_bf16(xb[kk + 1], bfm1, sa1, 0, 0, 0);
    }
    // ---- softmax part 1 (own 16-p tile) ----
    float v[4], ew[4];
    const float aqv = aqsL[h * 64 + q];
    const float* rel_h = &relLh[h * 169];
    float mw = -1e30f;
#pragma unroll
    for (int r = 0; r < 4; ++r) {
      const int p = wpt * 16 + quad * 4 + r;
      float val = -1e30f;
      if (p < 49) {
        const int yp = div7(p), xp = p - yp * 7;
        const int fp = regof(gi * 7 + yp) * 3 + regof(gj * 7 + xp);
        val = (sa0[r] + sa1[r] + aqv + bpsL[h * 64 + p]) * 0.0625f +
              rel_h[(yp - yq + 6) + 13 * (xp - xq + 6)];
        if (fp != fq) val -= 100.f;
      }
      v[r] = val;
      mw = fmaxf(mw, val);
    }
    mw = fmaxf(mw, __shfl_xor(mw, 16));
    mw = fmaxf(mw, __shfl_xor(mw, 32));
    float sw = 0.f;
#pragma unroll
    for (int r = 0; r < 4; ++r) { ew[r] = __expf(v[r] - mw); sw += ew[r]; }
    sw += __shfl_xor(sw, 16);
    sw += __shfl_xor(sw, 32);
    if (lane < 16) { mPart[wpt][wq * 16 + lane] = mw; sPart[wpt][wq * 16 + lane] = sw; }
    __syncthreads();                                  // BAR A
    // ---- softmax part 2: 4-way combine, write StB 16x16 block ----
    {
      const float m0 = mPart[0][q], m1 = mPart[1][q];
      const float m2 = mPart[2][q], m3 = mPart[3][q];
      const float mg = fmaxf(fmaxf(m0, m1), fmaxf(m2, m3));
      const float tot = sPart[0][q] * __expf(m0 - mg) + sPart[1][q] * __expf(m1 - mg) +
                        sPart[2][q] * __expf(m2 - mg) + sPart[3][q] * __expf(m3 - mg);
      const float scale = __expf(mw - mg) / tot;
      ushort4 u;
      u.x = f2b(ew[0] * scale); u.y = f2b(ew[1] * scale);
      u.z = f2b(ew[2] * scale); u.w = f2b(ew[3] * scale);
      *(ushort4*)(&StB[q * 72 + wpt * 16 + quad * 4]) = u;
    }
    if (h < 7) m_step(h + 1);   // Msm(h) reads all done (BAR A passed)
    __syncthreads();                                  // BAR C
    // ---- wfr chunk A prefetch (L2), latency hidden under PV ----
    const ushort_t* Wb = Wov3 + (size_t)(wo * 32 + l16) * 2048 + h * 256 + quad * 8;
    bf16x8 wfrA[2][4];
#pragma unroll
    for (int i = 0; i < 2; ++i)
#pragma unroll
      for (int k = 0; k < 4; ++k)
        wfrA[i][k] = *(const bf16x8*)(Wb + (size_t)i * 16 * 2048 + k * 32);
    // ---- PV: T^T[q][d], 2 q-tiles x 2 d-tiles per wave ----
    {
      f32x4 tacc[2][2];
#pragma unroll
      for (int a = 0; a < 2; ++a)
#pragma unroll
        for (int b = 0; b < 2; ++b) tacc[a][b] = (f32x4){0.f, 0.f, 0.f, 0.f};
#pragma unroll
      for (int kk = 0; kk < 2; ++kk)
#pragma unroll
        for (int qt = 0; qt < 2; ++qt) {
          bf16x8 bfw = *(const bf16x8*)(&StB[((qp * 2 + qt) * 16 + l16) * 72 + kk * 32 + quad * 8]);
#pragma unroll
          for (int dt = 0; dt < 2; ++dt)
            tacc[qt][dt] = __builtin_amdgcn_mfma_f32_16x16x32_bf16(xfr[dt][kk], bfw, tacc[qt][dt], 0, 0, 0);
        }
#pragma unroll
      for (int qt = 0; qt < 2; ++qt)
#pragma unroll
        for (int dt = 0; dt < 2; ++dt)
          *(ushort4*)(&Tsm[((qp * 2 + qt) * 16 + l16) * FSTR + (dg * 2 + dt) * 16 + quad * 4]) =
              pack4(tacc[qt][dt]);
    }
    __syncthreads();                                  // BAR D
    // ---- out-step: oacc[o 2x16][q 2x16] += Wov3_h . T^T (2 wfr chunks) ----
#pragma unroll
    for (int k = 0; k < 4; ++k)
#pragma unroll
      for (int qt = 0; qt < 2; ++qt) {
        bf16x8 bfo = *(const bf16x8*)(&Tsm[((wq2 * 2 + qt) * 16 + l16) * FSTR + k * 32 + quad * 8]);
#pragma unroll
        for (int i = 0; i < 2; ++i)
          oacc[i][qt] = __builtin_amdgcn_mfma_f32_16x16x32_bf16(wfrA[i][k], bfo, oacc[i][qt], 0, 0, 0);
      }
    bf16x8 wfrB[2][4];
#pragma unroll
    for (int i = 0; i < 2; ++i)
#pragma unroll
      for (int k = 0; k < 4; ++k)
        wfrB[i][k] = *(const bf16x8*)(Wb + (size_t)i * 16 * 2048 + (4 + k) * 32);
#pragma unroll
    for (int k = 0; k < 4; ++k)
#pragma unroll
      for (int qt = 0; qt < 2; ++qt) {
        bf16x8 bfo = *(const bf16x8*)(&Tsm[((wq2 * 2 + qt) * 16 + l16) * FSTR + (4 + k) * 32 + quad * 8]);
#pragma unroll
        for (int i = 0; i < 2; ++i)
          oacc[i][qt] = __builtin_amdgcn_mfma_f32_16x16x32_bf16(wfrB[i][k], bfo, oacc[i][qt], 0, 0, 0);
      }
    // no barrier: next head's BAR A/C order Tsm & Msm reuse
  }
  // ---- epilogue: out[o][t2] = oacc + cvec ----
#pragma unroll
  for (int i = 0; i < 2; ++i) {
    const int ob = wo * 32 + i * 16 + quad * 4;
    const float4 cv = *(const float4*)(cvec + ob);
#pragma unroll
    for (int qt = 0; qt < 2; ++qt) {
      const int q2 = (wq2 * 2 + qt) * 16 + l16;
      if (q2 < 49) {
        const int t2 = tmap(q2, gi, gj);
        on[(size_t)(ob + 0) * 3136 + t2] = oacc[i][qt][0] + cv.x;
        on[(size_t)(ob + 1) * 3136 + t2] = oacc[i][qt][1] + cv.y;
        on[(size_t)(ob + 2) * 3136 + t2] = oacc[i][qt][2] + cv.z;
        on[(size_t)(ob + 3) * 3136 + t2] = oacc[i][qt][3] + cv.w;
      }
    }
  }
}

extern "C" void kernel_launch(void* const* d_in, const int* in_sizes, int n_in,
                              void* d_out, int out_size, void* d_ws, size_t ws_size,
                              hipStream_t stream) {
  (void)in_sizes; (void)n_in; (void)out_size; (void)ws_size;
  const float* X  = (const float*)d_in[0];
  const float* Wk = (const float*)d_in[1];
  const float* bk = (const float*)d_in[2];
  const float* Wq = (const float*)d_in[3];
  const float* bq = (const float*)d_in[4];
  const float* Wv = (const float*)d_in[5];
  const float* bv = (const float*)d_in[6];
  const float* Wo = (const float*)d_in[7];
  const float* bo = (const float*)d_in[8];
  const float* rc = (const float*)d_in[9];

  ushort_t* Xroll = (ushort_t*)d_ws;                       // 8*3200*256 u16
  ushort_t* Aext  = Xroll + (size_t)8 * TROWS * 256;       // 2176*256 u16
  ushort_t* Wov3  = Aext + 2176 * 256;                     // 256*2048 u16
  float* fbase = (float*)(Wov3 + 256 * 2048);
  float* cvec  = fbase;         // 256 f32
  float* relL2 = fbase + 256;   // 8*169 f32
  float* out = (float*)d_out;

  k_prep <<<dim3(1290), dim3(256), 0, stream>>>(Wk, Wq, Wo, Wv, bk, bq, bv, bo, rc,
                                                Aext, Wov3, cvec, relL2);
  k_conv <<<dim3(8 * 57), dim3(256), 0, stream>>>(X, Xroll);
  k_fused<<<dim3(512), dim3(1024), 0, stream>>>(Xroll, Aext, Wov3, cvec, relL2, out);
}

// Round 8
// 404.734 us; speedup vs baseline: 1.0745x; 1.0745x over previous
//
#include <hip/hip_runtime.h>
#include <hip/hip_bf16.h>

// Swin window MHSA, MI355X, round 14.
//   k_prep : Aext[2176x256]=G'(+w1/w2 rows), Wov3[256x2048], cvec, relL2(+c0)
//   k_conv : X fp32 -> rolled bf16 Xroll (register-row, static-rotated stores)
//   k_fused: per (n,window): M=G'.X, S=Xp.M, softmax, T^T=X^T.w, out+=Wov3.T^T
//            R14: R13's 16-wave partitioning (correctness-verified) with the
//            register budget fixed. R13 spilled: 1024-thr block => hard 128
//            VGPR cap, live set ~150 => allocator fell to 64 VGPR + scratch
//            (WRITE_SIZE 25->115MB). R14 cuts peak live to ~90:
//              - no xb[8] hoist (S-step reads Xp per kk: +8 LDS reads/head)
//              - wfr as [2][2] chunks in a ROLLED (unroll 1) 4-iter loop
//              - keep xfr[2][2] + oacc[2][2]
//            Tripwire: VGPR_Count must be ~96-128 (64 => spill => abandon).

#define NBATCH 8
#define TROWS  3200           // padded token rows
#define FSTR   264            // LDS row stride for Xp/Msm/Tsm (bank-spread)

typedef unsigned short ushort_t;
typedef __attribute__((ext_vector_type(8))) short bf16x8;   // 8 bf16 = 4 VGPR
typedef __attribute__((ext_vector_type(8))) unsigned short u16x8;
typedef __attribute__((ext_vector_type(4))) float f32x4;    // MFMA acc

__device__ __forceinline__ float b2f(ushort_t u) {
  union { unsigned int i; float f; } v; v.i = ((unsigned int)u) << 16; return v.f;
}
__device__ __forceinline__ ushort_t f2b(float f) {
  union { float f; unsigned int u; } v; v.f = f;
  unsigned int u = v.u;
  return (ushort_t)((u + 0x7FFFu + ((u >> 16) & 1u)) >> 16);
}
__device__ __forceinline__ int regof(int y) { return (y < 49) ? 0 : ((y < 53) ? 1 : 2); }
__device__ __forceinline__ int div7(int t) { return (t * 37) >> 8; }  // t/7, t<64
__device__ __forceinline__ int tmap(int p, int gi, int gj) {
  int wi = div7(p); return (gi * 7 + wi) * 56 + gj * 7 + (p - wi * 7);
}
__device__ __forceinline__ ushort4 pack4(f32x4 a) {
  ushort4 u; u.x = f2b(a[0]); u.y = f2b(a[1]); u.z = f2b(a[2]); u.w = f2b(a[3]);
  return u;
}

// ================= prep (unchanged) =================
__global__ void k_prep(const float* __restrict__ Wk, const float* __restrict__ Wq,
                       const float* __restrict__ Wo, const float* __restrict__ Wv,
                       const float* __restrict__ bk, const float* __restrict__ bq,
                       const float* __restrict__ bv, const float* __restrict__ bo,
                       const float* __restrict__ relc,
                       ushort_t* __restrict__ Aext, ushort_t* __restrict__ Wov3,
                       float* __restrict__ cvec, float* __restrict__ relL2) {
  __shared__ float red[8];
  int blk = blockIdx.x, t = threadIdx.x;
  if (blk < 512) {
    int h = blk >> 6, b0 = (blk & 63) << 2, a = t;
    const float* wkh = Wk + h * 65536;
    const float* wqh = Wq + h * 65536;
    float a0 = 0.f, a1 = 0.f, a2 = 0.f, a3 = 0.f;
    for (int dd = 0; dd < 256; ++dd) {
      float wk = wkh[dd * 256 + a];
      float4 w4 = *(const float4*)(wqh + dd * 256 + b0);
      a0 += wk * w4.x; a1 += wk * w4.y; a2 += wk * w4.z; a3 += wk * w4.w;
    }
    ushort4 u; u.x = f2b(a0); u.y = f2b(a1); u.z = f2b(a2); u.w = f2b(a3);
    *(ushort4*)(Aext + (h * 256 + a) * 256 + b0) = u;
  } else if (blk < 1024) {
    int bb = blk - 512;
    int h = bb >> 6, o0 = (bb & 63) << 2, d = t;
    float a0 = 0.f, a1 = 0.f, a2 = 0.f, a3 = 0.f;
    for (int dd = 0; dd < 256; ++dd) {
      float wv = Wv[(h * 256 + dd) * 256 + d];
      a0 += Wo[(o0 + 0) * 2048 + h * 256 + dd] * wv;
      a1 += Wo[(o0 + 1) * 2048 + h * 256 + dd] * wv;
      a2 += Wo[(o0 + 2) * 2048 + h * 256 + dd] * wv;
      a3 += Wo[(o0 + 3) * 2048 + h * 256 + dd] * wv;
    }
    Wov3[(o0 + 0) * 2048 + h * 256 + d] = f2b(a0);
    Wov3[(o0 + 1) * 2048 + h * 256 + d] = f2b(a1);
    Wov3[(o0 + 2) * 2048 + h * 256 + d] = f2b(a2);
    Wov3[(o0 + 3) * 2048 + h * 256 + d] = f2b(a3);
  } else if (blk < 1032) {
    int h = blk - 1024;
    float s1 = 0.f, s2 = 0.f;
    for (int dd = 0; dd < 256; ++dd) {
      s1 += bk[h * 256 + dd] * Wq[(h * 256 + dd) * 256 + t];
      s2 += bq[h * 256 + dd] * Wk[(h * 256 + dd) * 256 + t];
    }
    Aext[(2048 + h) * 256 + t] = f2b(s1);
    Aext[(2056 + h) * 256 + t] = f2b(s2);
  } else if (blk == 1032) {
    for (int i = t; i < 112 * 256 / 8; i += 256)
      *(u16x8*)(Aext + 2064 * 256 + i * 8) = (u16x8){0,0,0,0,0,0,0,0};
  } else if (blk < 1289) {
    int o = blk - 1033;
    const float* wob = Wo + o * 2048;
    float acc = 0.f;
#pragma unroll
    for (int j = 0; j < 8; ++j) acc += wob[j * 256 + t] * bv[j * 256 + t];
#pragma unroll
    for (int s = 1; s < 64; s <<= 1) acc += __shfl_xor(acc, s);
    if ((t & 63) == 0) red[t >> 6] = acc;
    __syncthreads();
    if (t == 0) cvec[o] = bo[o] + red[0] + red[1] + red[2] + red[3];
  } else {
    if (t < 8) {
      float c = 0.f;
      for (int dd = 0; dd < 256; ++dd) c += bk[t * 256 + dd] * bq[t * 256 + dd];
      red[t] = c * 0.0625f;
    }
    __syncthreads();
    for (int i = t; i < 8 * 169; i += 256) {
      int h = i / 169, idx = i - h * 169;
      relL2[i] = relc[idx * 8 + h] + red[h];
    }
  }
}

// ================= conv: register-row, static-rotated stores ==============
__global__ void k_conv(const float* __restrict__ X, ushort_t* __restrict__ Xroll) {
  const int n = blockIdx.x / 57, y = blockIdx.x % 57;
  ushort_t* xr = Xroll + (size_t)n * TROWS * 256;
  const int d = threadIdx.x;
  if (y == 56) {  // zero pad rows 3136..3199
    for (int i = d; i < 64 * 256 / 8; i += 256)
      *(u16x8*)(xr + 3136 * 256 + i * 8) = (u16x8){0,0,0,0,0,0,0,0};
    return;
  }
  const int c = d >> 4, p1 = (d >> 2) & 3, p2 = d & 3;
  const int sp = c * 16 + (((p1 + 1) & 3) << 2) + ((p2 + 1) & 3);
  const int ty = (p1 == 3) ? y : ((y == 0) ? 55 : y - 1);
  const float* rowp = X + (size_t)n * 256 * 3136 + sp * 3136 + ty * 56;
  ushort_t* orow = xr + y * 56 * 256 + d;
  float row[56];
#pragma unroll
  for (int i = 0; i < 14; ++i) {
    const float4 t4 = ((const float4*)rowp)[i];
    row[i * 4 + 0] = t4.x; row[i * 4 + 1] = t4.y;
    row[i * 4 + 2] = t4.z; row[i * 4 + 3] = t4.w;
  }
  const bool nr = (p2 == 3);   // no roll along x for p2==3
#pragma unroll
  for (int x = 0; x < 56; ++x) {
    const float a = (x == 0) ? row[55] : row[x - 1];  // static indices
    orow[x * 256] = f2b(nr ? row[x] : a);   // 256 lanes -> 512B contiguous
  }
}

// ================= fused window attention (16 waves, spill-free) ==========
// Block = (n = XCD via bx&7, window g = bx>>3). 1024 threads = 16 waves.
// Roles: S/softmax (wq=wave&3, wpt=wave>>2); m_step (wb=wave&7, th=wave>>3);
//        PV (qp=wave&1, dg=wave>>1); out (wo=wave&7, wq2=wave>>3).
__global__ __launch_bounds__(1024, 4) void k_fused(
    const ushort_t* __restrict__ Xroll, const ushort_t* __restrict__ Aext,
    const ushort_t* __restrict__ Wov3, const float* __restrict__ cvec,
    const float* __restrict__ relL2, float* __restrict__ out) {
  __shared__ ushort_t Xp[64 * FSTR];     // X window tokens [t][d]
  __shared__ ushort_t Msm[64 * FSTR];    // M_h [q][b-local]
  __shared__ ushort_t Tsm[64 * FSTR];    // T^T [q][d]
  __shared__ ushort_t StB[64 * 72];      // wmap [q][p]
  __shared__ float aqsL[8 * 64];
  __shared__ float bpsL[8 * 64];
  __shared__ float relLh[8 * 169];
  __shared__ float mPart[4][64];
  __shared__ float sPart[4][64];

  const int tid = threadIdx.x;
  const int wave = tid >> 6, lane = tid & 63;
  const int quad = lane >> 4, l16 = lane & 15;
  const int n = blockIdx.x & 7, g = blockIdx.x >> 3;
  const int gi = g >> 3, gj = g & 7;
  const ushort_t* Xn = Xroll + (size_t)n * TROWS * 256;
  float* on = out + (size_t)n * 256 * 3136;

  // ---- stage Xp (rows >=49 zeroed); 16 cg x 2 chunks ----
  {
    const int p = tid & 63, cg = tid >> 6;
    if (p < 49) {
      int t = tmap(p, gi, gj);
#pragma unroll
      for (int i = 0; i < 2; ++i)
        *(u16x8*)(&Xp[p * FSTR + (cg * 2 + i) * 8]) =
            *(const u16x8*)(Xn + t * 256 + (cg * 2 + i) * 8);
    } else {
#pragma unroll
      for (int i = 0; i < 2; ++i)
        *(u16x8*)(&Xp[p * FSTR + (cg * 2 + i) * 8]) = (u16x8){0,0,0,0,0,0,0,0};
    }
  }
  for (int i = tid; i < 8 * 169; i += 1024) relLh[i] = relL2[i];
  __syncthreads();

  const int wq  = wave & 3,  wpt = wave >> 2;   // S/softmax role
  const int wb  = wave & 7,  th  = wave >> 3;   // m_step role
  const int qp  = wave & 1,  dg  = wave >> 1;   // PV role
  const int wo  = wave & 7,  wq2 = wave >> 3;   // out role

  // ---- xfr: PV A-frags (X^T), d-tiles dg*2+{0,1} (16 VGPR, kept) ----
  bf16x8 xfr[2][2];
#pragma unroll
  for (int dt = 0; dt < 2; ++dt) {
    const int dcol = (dg * 2 + dt) * 16 + l16;
#pragma unroll
    for (int kk = 0; kk < 2; ++kk)
#pragma unroll
      for (int j = 0; j < 8; ++j)
        xfr[dt][kk][j] = (short)Xp[(kk * 32 + quad * 8 + j) * FSTR + dcol];
  }

  // ---- m_step: M_h[t][b], 16 waves: 32 b-cols x 32 tokens each ----
  auto m_step = [&](int h) {
    f32x4 macc[2][2];
#pragma unroll
    for (int i = 0; i < 2; ++i)
#pragma unroll
      for (int t = 0; t < 2; ++t) macc[i][t] = (f32x4){0.f, 0.f, 0.f, 0.f};
    const ushort_t* Ah =
        Aext + (size_t)(h * 256 + wb * 32 + l16) * 256 + quad * 8;
#pragma unroll
    for (int kk = 0; kk < 8; ++kk) {
      bf16x8 ga[2];
#pragma unroll
      for (int i = 0; i < 2; ++i)
        ga[i] = *(const bf16x8*)(Ah + i * 16 * 256 + kk * 32);
#pragma unroll
      for (int t = 0; t < 2; ++t) {
        bf16x8 bx_ = *(const bf16x8*)(&Xp[(th * 32 + t * 16 + l16) * FSTR + kk * 32 + quad * 8]);
#pragma unroll
        for (int i = 0; i < 2; ++i)
          macc[i][t] = __builtin_amdgcn_mfma_f32_16x16x32_bf16(ga[i], bx_, macc[i][t], 0, 0, 0);
      }
    }
#pragma unroll
    for (int i = 0; i < 2; ++i)
#pragma unroll
      for (int t = 0; t < 2; ++t)
        *(ushort4*)(&Msm[(th * 32 + t * 16 + l16) * FSTR + wb * 32 + i * 16 + quad * 4]) =
            pack4(macc[i][t]);
  };

  m_step(0);
  if (wave == 0) {
    // Mext: rows 2048..2063 of Aext -> aqs (w1) / bps (w2) per token, f32
    f32x4 eacc[4];
#pragma unroll
    for (int t = 0; t < 4; ++t) eacc[t] = (f32x4){0.f, 0.f, 0.f, 0.f};
    const ushort_t* Ae = Aext + (size_t)(2048 + l16) * 256 + quad * 8;
#pragma unroll
    for (int kk = 0; kk < 8; ++kk) {
      bf16x8 ea = *(const bf16x8*)(Ae + kk * 32);
#pragma unroll
      for (int t = 0; t < 4; ++t) {
        bf16x8 bx_ = *(const bf16x8*)(&Xp[(t * 16 + l16) * FSTR + kk * 32 + quad * 8]);
        eacc[t] = __builtin_amdgcn_mfma_f32_16x16x32_bf16(ea, bx_, eacc[t], 0, 0, 0);
      }
    }
#pragma unroll
    for (int t = 0; t < 4; ++t) {
      const int tok = t * 16 + l16;
#pragma unroll
      for (int r = 0; r < 4; ++r) {
        const int e = quad * 4 + r;
        if (e < 8) aqsL[e * 64 + tok] = eacc[t][r];
        else       bpsL[(e - 8) * 64 + tok] = eacc[t][r];
      }
    }
  }
  __syncthreads();

  const int q = wq * 16 + l16;
  const int qq = (q < 49) ? q : 48;
  const int yq = div7(qq), xq = qq - yq * 7;
  const int fq = regof(gi * 7 + yq) * 3 + regof(gj * 7 + xq);

  f32x4 oacc[2][2];
#pragma unroll
  for (int i = 0; i < 2; ++i)
#pragma unroll
    for (int j = 0; j < 2; ++j) oacc[i][j] = (f32x4){0.f, 0.f, 0.f, 0.f};

  for (int h = 0; h < 8; ++h) {
    // ---- S-step: 16x16 tile (p-tile wpt x q-tile wq), dual chains,
    //      operands straight from LDS (no xb hoist) ----
    f32x4 sa0 = (f32x4){0.f,0.f,0.f,0.f}, sa1 = (f32x4){0.f,0.f,0.f,0.f};
#pragma unroll
    for (int kk = 0; kk < 8; kk += 2) {
      bf16x8 xb0 = *(const bf16x8*)(&Xp[(wpt * 16 + l16) * FSTR + kk * 32 + quad * 8]);
      bf16x8 xb1 = *(const bf16x8*)(&Xp[(wpt * 16 + l16) * FSTR + (kk + 1) * 32 + quad * 8]);
      bf16x8 bfm0 = *(const bf16x8*)(&Msm[q * FSTR + kk * 32 + quad * 8]);
      bf16x8 bfm1 = *(const bf16x8*)(&Msm[q * FSTR + (kk + 1) * 32 + quad * 8]);
      sa0 = __builtin_amdgcn_mfma_f32_16x16x32_bf16(xb0, bfm0, sa0, 0, 0, 0);
      sa1 = __builtin_amdgcn_mfma_f32_16x16x32_bf16(xb1, bfm1, sa1, 0, 0, 0);
    }
    // ---- softmax part 1 (own 16-p tile) ----
    float v[4], ew[4];
    const float aqv = aqsL[h * 64 + q];
    const float* rel_h = &relLh[h * 169];
    float mw = -1e30f;
#pragma unroll
    for (int r = 0; r < 4; ++r) {
      const int p = wpt * 16 + quad * 4 + r;
      float val = -1e30f;
      if (p < 49) {
        const int yp = div7(p), xp = p - yp * 7;
        const int fp = regof(gi * 7 + yp) * 3 + regof(gj * 7 + xp);
        val = (sa0[r] + sa1[r] + aqv + bpsL[h * 64 + p]) * 0.0625f +
              rel_h[(yp - yq + 6) + 13 * (xp - xq + 6)];
        if (fp != fq) val -= 100.f;
      }
      v[r] = val;
      mw = fmaxf(mw, val);
    }
    mw = fmaxf(mw, __shfl_xor(mw, 16));
    mw = fmaxf(mw, __shfl_xor(mw, 32));
    float sw = 0.f;
#pragma unroll
    for (int r = 0; r < 4; ++r) { ew[r] = __expf(v[r] - mw); sw += ew[r]; }
    sw += __shfl_xor(sw, 16);
    sw += __shfl_xor(sw, 32);
    if (lane < 16) { mPart[wpt][wq * 16 + lane] = mw; sPart[wpt][wq * 16 + lane] = sw; }
    __syncthreads();                                  // BAR A
    // ---- softmax part 2: 4-way combine, write StB 16x16 block ----
    {
      const float m0 = mPart[0][q], m1 = mPart[1][q];
      const float m2 = mPart[2][q], m3 = mPart[3][q];
      const float mg = fmaxf(fmaxf(m0, m1), fmaxf(m2, m3));
      const float tot = sPart[0][q] * __expf(m0 - mg) + sPart[1][q] * __expf(m1 - mg) +
                        sPart[2][q] * __expf(m2 - mg) + sPart[3][q] * __expf(m3 - mg);
      const float scale = __expf(mw - mg) / tot;
      ushort4 u;
      u.x = f2b(ew[0] * scale); u.y = f2b(ew[1] * scale);
      u.z = f2b(ew[2] * scale); u.w = f2b(ew[3] * scale);
      *(ushort4*)(&StB[q * 72 + wpt * 16 + quad * 4]) = u;
    }
    if (h < 7) m_step(h + 1);   // Msm(h) reads all done (BAR A passed)
    __syncthreads();                                  // BAR C
    // ---- PV: T^T[q][d], 2 q-tiles x 2 d-tiles per wave ----
    {
      f32x4 tacc[2][2];
#pragma unroll
      for (int a = 0; a < 2; ++a)
#pragma unroll
        for (int b = 0; b < 2; ++b) tacc[a][b] = (f32x4){0.f, 0.f, 0.f, 0.f};
#pragma unroll
      for (int kk = 0; kk < 2; ++kk)
#pragma unroll
        for (int qt = 0; qt < 2; ++qt) {
          bf16x8 bfw = *(const bf16x8*)(&StB[((qp * 2 + qt) * 16 + l16) * 72 + kk * 32 + quad * 8]);
#pragma unroll
          for (int dt = 0; dt < 2; ++dt)
            tacc[qt][dt] = __builtin_amdgcn_mfma_f32_16x16x32_bf16(xfr[dt][kk], bfw, tacc[qt][dt], 0, 0, 0);
        }
#pragma unroll
      for (int qt = 0; qt < 2; ++qt)
#pragma unroll
        for (int dt = 0; dt < 2; ++dt)
          *(ushort4*)(&Tsm[((qp * 2 + qt) * 16 + l16) * FSTR + (dg * 2 + dt) * 16 + quad * 4]) =
              pack4(tacc[qt][dt]);
    }
    __syncthreads();                                  // BAR D
    // ---- out-step: rolled 4-chunk loop, wfr chunk = [2][2] (16 VGPR) ----
    const ushort_t* Wb = Wov3 + (size_t)(wo * 32 + l16) * 2048 + h * 256 + quad * 8;
#pragma unroll 1
    for (int c = 0; c < 4; ++c) {
      bf16x8 wf[2][2];
#pragma unroll
      for (int i = 0; i < 2; ++i)
#pragma unroll
        for (int k = 0; k < 2; ++k)
          wf[i][k] = *(const bf16x8*)(Wb + (size_t)i * 16 * 2048 + (c * 2 + k) * 32);
#pragma unroll
      for (int k = 0; k < 2; ++k)
#pragma unroll
        for (int qt = 0; qt < 2; ++qt) {
          bf16x8 bfo = *(const bf16x8*)(&Tsm[((wq2 * 2 + qt) * 16 + l16) * FSTR + (c * 2 + k) * 32 + quad * 8]);
#pragma unroll
          for (int i = 0; i < 2; ++i)
            oacc[i][qt] = __builtin_amdgcn_mfma_f32_16x16x32_bf16(wf[i][k], bfo, oacc[i][qt], 0, 0, 0);
        }
    }
    // no barrier: next head's BAR A/C order Tsm & Msm reuse
  }
  // ---- epilogue: out[o][t2] = oacc + cvec ----
#pragma unroll
  for (int i = 0; i < 2; ++i) {
    const int ob = wo * 32 + i * 16 + quad * 4;
    const float4 cv = *(const float4*)(cvec + ob);
#pragma unroll
    for (int qt = 0; qt < 2; ++qt) {
      const int q2 = (wq2 * 2 + qt) * 16 + l16;
      if (q2 < 49) {
        const int t2 = tmap(q2, gi, gj);
        on[(size_t)(ob + 0) * 3136 + t2] = oacc[i][qt][0] + cv.x;
        on[(size_t)(ob + 1) * 3136 + t2] = oacc[i][qt][1] + cv.y;
        on[(size_t)(ob + 2) * 3136 + t2] = oacc[i][qt][2] + cv.z;
        on[(size_t)(ob + 3) * 3136 + t2] = oacc[i][qt][3] + cv.w;
      }
    }
  }
}

extern "C" void kernel_launch(void* const* d_in, const int* in_sizes, int n_in,
                              void* d_out, int out_size, void* d_ws, size_t ws_size,
                              hipStream_t stream) {
  (void)in_sizes; (void)n_in; (void)out_size; (void)ws_size;
  const float* X  = (const float*)d_in[0];
  const float* Wk = (const float*)d_in[1];
  const float* bk = (const float*)d_in[2];
  const float* Wq = (const float*)d_in[3];
  const float* bq = (const float*)d_in[4];
  const float* Wv = (const float*)d_in[5];
  const float* bv = (const float*)d_in[6];
  const float* Wo = (const float*)d_in[7];
  const float* bo = (const float*)d_in[8];
  const float* rc = (const float*)d_in[9];

  ushort_t* Xroll = (ushort_t*)d_ws;                       // 8*3200*256 u16
  ushort_t* Aext  = Xroll + (size_t)8 * TROWS * 256;       // 2176*256 u16
  ushort_t* Wov3  = Aext + 2176 * 256;                     // 256*2048 u16
  float* fbase = (float*)(Wov3 + 256 * 2048);
  float* cvec  = fbase;         // 256 f32
  float* relL2 = fbase + 256;   // 8*169 f32
  float* out = (float*)d_out;

  k_prep <<<dim3(1290), dim3(256), 0, stream>>>(Wk, Wq, Wo, Wv, bk, bq, bv, bo, rc,
                                                Aext, Wov3, cvec, relL2);
  k_conv <<<dim3(8 * 57), dim3(256), 0, stream>>>(X, Xroll);
  k_fused<<<dim3(512), dim3(1024), 0, stream>>>(Xroll, Aext, Wov3, cvec, relL2, out);
}

// Round 9
// 293.483 us; speedup vs baseline: 1.4818x; 1.3791x over previous
//
#include <hip/hip_runtime.h>
#include <hip/hip_bf16.h>

// Swin window MHSA, MI355X, round 15.
//   REVERT to R9 pipeline (session best, 274us): prep / conv / gemm1
//   (persistent counted-vmcnt, 119 blk/XCD) / attn2 / gemm3.
//   Mega-fused k_fused abandoned: 122KB LDS => 1 block/CU => no independent
//   work to hide phase latency; 4 rounds never beat the unfused chain.
//   ONE change vs R9: k_conv rewritten as LDS-transpose. Old conv's lanes
//   each addressed a DIFFERENT input row (sp varies with lane) => every
//   load = 64 scattered line transactions; ~80us hidden in totals.
//   New conv: wave-uniform (sp,ty) per d, lane = tx => 1 load = 4 lines;
//   x-roll folded into the LDS write index; Lx[256][57] pad => both
//   phases bank-conflict-free.

#define NBATCH 8
#define MSTR   2176           // M_T / T_T row stride (a'-dim, 17 tiles of 128)
#define TROWS  3200           // padded token rows (50 tiles of 64)

typedef unsigned short ushort_t;
typedef __attribute__((ext_vector_type(8))) short bf16x8;   // 8 bf16 = 4 VGPR
typedef __attribute__((ext_vector_type(8))) unsigned short u16x8;
typedef __attribute__((ext_vector_type(4))) float f32x4;    // MFMA acc

__device__ __forceinline__ float b2f(ushort_t u) {
  union { unsigned int i; float f; } v; v.i = ((unsigned int)u) << 16; return v.f;
}
__device__ __forceinline__ ushort_t f2b(float f) {
  union { float f; unsigned int u; } v; v.f = f;
  unsigned int u = v.u;
  return (ushort_t)((u + 0x7FFFu + ((u >> 16) & 1u)) >> 16);
}
__device__ __forceinline__ int regof(int y) { return (y < 49) ? 0 : ((y < 53) ? 1 : 2); }
__device__ __forceinline__ int div7(int t) { return (t * 37) >> 8; }  // t/7, t<64
__device__ __forceinline__ int tmap(int p, int gi, int gj) {
  int wi = div7(p); return (gi * 7 + wi) * 56 + gj * 7 + (p - wi * 7);
}
__device__ __forceinline__ ushort4 pack4(f32x4 a) {
  ushort4 u; u.x = f2b(a[0]); u.y = f2b(a[1]); u.z = f2b(a[2]); u.w = f2b(a[3]);
  return u;
}
// async global->LDS, 16B per lane; lds dest must be wave-uniform base
__device__ __forceinline__ void gload_lds16(const ushort_t* g, ushort_t* l) {
  __builtin_amdgcn_global_load_lds(
      (const __attribute__((address_space(1))) void*)g,
      (__attribute__((address_space(3))) void*)l, 16, 0, 0);
}
__device__ __forceinline__ void sb0() { __builtin_amdgcn_sched_barrier(0); }

// ================= prep (unchanged) =================
__global__ void k_prep(const float* __restrict__ Wk, const float* __restrict__ Wq,
                       const float* __restrict__ Wo, const float* __restrict__ Wv,
                       const float* __restrict__ bk, const float* __restrict__ bq,
                       const float* __restrict__ bv, const float* __restrict__ bo,
                       const float* __restrict__ relc,
                       ushort_t* __restrict__ Aext, ushort_t* __restrict__ Wov3,
                       float* __restrict__ cvec, float* __restrict__ relL2) {
  __shared__ float red[8];
  int blk = blockIdx.x, t = threadIdx.x;
  if (blk < 512) {
    int h = blk >> 6, b0 = (blk & 63) << 2, a = t;
    const float* wkh = Wk + h * 65536;
    const float* wqh = Wq + h * 65536;
    float a0 = 0.f, a1 = 0.f, a2 = 0.f, a3 = 0.f;
    for (int dd = 0; dd < 256; ++dd) {
      float wk = wkh[dd * 256 + a];
      float4 w4 = *(const float4*)(wqh + dd * 256 + b0);
      a0 += wk * w4.x; a1 += wk * w4.y; a2 += wk * w4.z; a3 += wk * w4.w;
    }
    ushort4 u; u.x = f2b(a0); u.y = f2b(a1); u.z = f2b(a2); u.w = f2b(a3);
    *(ushort4*)(Aext + (h * 256 + a) * 256 + b0) = u;
  } else if (blk < 1024) {
    int bb = blk - 512;
    int h = bb >> 6, o0 = (bb & 63) << 2, d = t;
    float a0 = 0.f, a1 = 0.f, a2 = 0.f, a3 = 0.f;
    for (int dd = 0; dd < 256; ++dd) {
      float wv = Wv[(h * 256 + dd) * 256 + d];
      a0 += Wo[(o0 + 0) * 2048 + h * 256 + dd] * wv;
      a1 += Wo[(o0 + 1) * 2048 + h * 256 + dd] * wv;
      a2 += Wo[(o0 + 2) * 2048 + h * 256 + dd] * wv;
      a3 += Wo[(o0 + 3) * 2048 + h * 256 + dd] * wv;
    }
    Wov3[(o0 + 0) * 2048 + h * 256 + d] = f2b(a0);
    Wov3[(o0 + 1) * 2048 + h * 256 + d] = f2b(a1);
    Wov3[(o0 + 2) * 2048 + h * 256 + d] = f2b(a2);
    Wov3[(o0 + 3) * 2048 + h * 256 + d] = f2b(a3);
  } else if (blk < 1032) {
    int h = blk - 1024;
    float s1 = 0.f, s2 = 0.f;
    for (int dd = 0; dd < 256; ++dd) {
      s1 += bk[h * 256 + dd] * Wq[(h * 256 + dd) * 256 + t];
      s2 += bq[h * 256 + dd] * Wk[(h * 256 + dd) * 256 + t];
    }
    Aext[(2048 + h) * 256 + t] = f2b(s1);
    Aext[(2056 + h) * 256 + t] = f2b(s2);
  } else if (blk == 1032) {
    for (int i = t; i < 112 * 256 / 8; i += 256)
      *(u16x8*)(Aext + 2064 * 256 + i * 8) = (u16x8){0,0,0,0,0,0,0,0};
  } else if (blk < 1289) {
    int o = blk - 1033;
    const float* wob = Wo + o * 2048;
    float acc = 0.f;
#pragma unroll
    for (int j = 0; j < 8; ++j) acc += wob[j * 256 + t] * bv[j * 256 + t];
#pragma unroll
    for (int s = 1; s < 64; s <<= 1) acc += __shfl_xor(acc, s);
    if ((t & 63) == 0) red[t >> 6] = acc;
    __syncthreads();
    if (t == 0) cvec[o] = bo[o] + red[0] + red[1] + red[2] + red[3];
  } else {
    if (t < 8) {
      float c = 0.f;
      for (int dd = 0; dd < 256; ++dd) c += bk[t * 256 + dd] * bq[t * 256 + dd];
      red[t] = c * 0.0625f;
    }
    __syncthreads();
    for (int i = t; i < 8 * 169; i += 256) {
      int h = i / 169, idx = i - h * 169;
      relL2[i] = relc[idx * 8 + h] + red[h];
    }
  }
}

// ================= conv: LDS-transpose, coalesced both sides ==============
__global__ void k_conv(const float* __restrict__ X, ushort_t* __restrict__ Xroll) {
  __shared__ float Lx[256 * 57];   // pad 57: both phases conflict-free
  const int n = blockIdx.x / 57, y = blockIdx.x % 57;
  ushort_t* xr = Xroll + (size_t)n * TROWS * 256;
  const int tid = threadIdx.x;
  if (y == 56) {  // zero pad rows 3136..3199
    for (int i = tid; i < 64 * 256 / 8; i += 256)
      *(u16x8*)(xr + 3136 * 256 + i * 8) = (u16x8){0,0,0,0,0,0,0,0};
    return;
  }
  const int wave = tid >> 6, lane = tid & 63;
  const float* Xn = X + (size_t)n * 256 * 3136;
  // phase 1: per d, (sp,ty) are wave-uniform; lane = tx -> one 224B
  // coalesced load per row (4 lines, vs 64 scattered lines before).
  // x-roll folded into the LDS write index (x s.t. tx(x)=lane).
#pragma unroll 8
  for (int dd = 0; dd < 64; ++dd) {
    const int d = wave * 64 + dd;
    const int c = d >> 4, p1 = (d >> 2) & 3, p2 = d & 3;
    const int sp = c * 16 + (((p1 + 1) & 3) << 2) + ((p2 + 1) & 3);
    const int ty = (p1 == 3) ? y : ((y == 0) ? 55 : y - 1);
    if (lane < 56) {
      const float val = Xn[(size_t)sp * 3136 + ty * 56 + lane];
      const int x = (p2 == 3) ? lane : ((lane == 55) ? 0 : lane + 1);
      Lx[d * 57 + x] = val;
    }
  }
  __syncthreads();
  // phase 2: lane = d; 56 x 512B coalesced bf16 row stores (as before)
  ushort_t* orow = xr + y * 56 * 256 + tid;
  const float* lrow = &Lx[tid * 57];
#pragma unroll
  for (int x = 0; x < 56; ++x)
    orow[x * 256] = f2b(lrow[x]);
}

// ================= gemm1: M_T[t][a'] = Xroll . Aext^T =====================
// R9 persistent pipelined version (session best). Block = (n=XCD, aa, chunk).
__global__ __launch_bounds__(256, 2) void k_gemm1(
    const ushort_t* __restrict__ Xroll, const ushort_t* __restrict__ Aext,
    ushort_t* __restrict__ MT) {
  __shared__ ushort_t Bsm[2][64 * 256];   // 2 x 32 KB
  const int bx0 = blockIdx.x;
  const int n = bx0 & 7;                  // XCD-bijective: XCD k owns batch k
  const int inner = bx0 >> 3;             // 0..118
  const int aa = inner % 17;
  const int c  = inner / 17;              // chunk 0..6
  const int a0 = aa * 128;
  const int tstart = (c == 0) ? 0 : (7 * c + 1);  // in 64-row tiles
  const int T = (c == 0) ? 8 : 7;                 // 8 + 6x7 = 50 tiles
  const int tid = threadIdx.x, wave = tid >> 6, lane = tid & 63;
  const int quad = lane >> 4, l16 = lane & 15;
  const int wa = wave >> 1, wt = wave & 1;
  const ushort_t* Xn = Xroll + (size_t)n * TROWS * 256;
  ushort_t* Mn = MT + (size_t)n * TROWS * MSTR;

  // ---- A-slice into regs: wave owns rows [a0+wa*64, +64), full K ----
  const ushort_t* abase = Aext + (size_t)(a0 + wa * 64 + l16) * 256 + quad * 8;
  bf16x8 areg[8][4];
#pragma unroll
  for (int kk = 0; kk < 8; ++kk)
#pragma unroll
    for (int i = 0; i < 4; ++i)
      areg[kk][i] = *(const bf16x8*)(abase + i * 4096 + kk * 32);   // 32 loads
  sb0();

  // ---- DMA fill of one 64x256 tile (swizzled), 8 insts/wave ----
  auto fill = [&](int mt, int b) {
    const ushort_t* src = Xn + (size_t)(tstart + mt) * 64 * 256;
#pragma unroll
    for (int i = 0; i < 8; ++i) {
      int S = i * 256 + tid;
      int rr = S >> 5, sc = S & 31;
      int cc = (sc & 24) | ((sc ^ rr) & 7);
      gload_lds16(src + rr * 256 + cc * 8, &Bsm[b][(i * 256 + wave * 64) * 8]);
    }
  };

  fill(0, 0); sb0();
  fill(1, 1); sb0();
  // outstanding: A(32), f0(8), f1(8). vmcnt(8) => A + f0 complete.
  asm volatile("s_waitcnt vmcnt(8)" ::: "memory"); sb0();
  __builtin_amdgcn_s_barrier(); sb0();

  const int sw = l16 & 7;
  for (int m = 0; m < T; ++m) {
    if (m > 0) {
      // need fill(m) done. Issued after it: stores(m-1)[8] (+ fill(m+1)[8]).
      if (m + 1 < T) { asm volatile("s_waitcnt vmcnt(16)" ::: "memory"); }
      else           { asm volatile("s_waitcnt vmcnt(8)"  ::: "memory"); }
      sb0();
      __builtin_amdgcn_s_barrier(); sb0();
    }
    const int b = m & 1;
    f32x4 acc[4][2];
#pragma unroll
    for (int i = 0; i < 4; ++i)
#pragma unroll
      for (int j = 0; j < 2; ++j) acc[i][j] = (f32x4){0.f, 0.f, 0.f, 0.f};
#pragma unroll
    for (int kk = 0; kk < 8; ++kk) {
      bf16x8 bfj[2];
#pragma unroll
      for (int j = 0; j < 2; ++j) {
        int rr = wt * 32 + j * 16 + l16;
        int cc = kk * 4 + quad;
        int pos = (cc & 24) | ((cc ^ sw) & 7);
        bfj[j] = *(const bf16x8*)(&Bsm[b][rr * 256 + pos * 8]);
      }
#pragma unroll
      for (int i = 0; i < 4; ++i)
#pragma unroll
        for (int j = 0; j < 2; ++j)
          acc[i][j] = __builtin_amdgcn_mfma_f32_16x16x32_bf16(areg[kk][i], bfj[j], acc[i][j], 0, 0, 0);
    }
    // stores: 8 per wave (counted in the vmcnt schedule)
    const int tb = (tstart + m) * 64;
#pragma unroll
    for (int i = 0; i < 4; ++i)
#pragma unroll
      for (int j = 0; j < 2; ++j) {
        int tg = tb + wt * 32 + j * 16 + l16;
        int ag = a0 + wa * 64 + i * 16 + quad * 4;
        *(ushort4*)(Mn + (size_t)tg * MSTR + ag) = pack4(acc[i][j]);
      }
    sb0();
    __builtin_amdgcn_s_barrier(); sb0();   // all waves done reading buf b
    if (m + 2 < T) { fill(m + 2, b); sb0(); }
  }
}

// ================= attn2 (unchanged) ==============================
#define XP_STR 264
__global__ __launch_bounds__(512, 4) void k_attn2(
    const ushort_t* __restrict__ Xroll, ushort_t* __restrict__ MT,
    const float* __restrict__ relL2) {
  __shared__ ushort_t Xp[64 * XP_STR];
  __shared__ ushort_t StB[2][64 * 72];
  __shared__ float aqsL[8 * 64];
  __shared__ float bpsL[8 * 64];
  __shared__ float relLh[8 * 169];

  const int tid = threadIdx.x;
  const int wave = tid >> 6, lane = tid & 63;
  const int quad = lane >> 4, l16 = lane & 15;
  const int group = wave >> 2, wv = wave & 3;
  const int n = blockIdx.x >> 6, g = blockIdx.x & 63;
  const int gi = g >> 3, gj = g & 7;
  const ushort_t* Xn = Xroll + (size_t)n * TROWS * 256;
  ushort_t* Mn = MT + (size_t)n * TROWS * MSTR;

  {
    const int p = tid & 63, cg = tid >> 6;
    if (p < 49) {
      int t = tmap(p, gi, gj);
#pragma unroll
      for (int i = 0; i < 4; ++i)
        *(u16x8*)(&Xp[p * XP_STR + (cg * 4 + i) * 8]) =
            *(const u16x8*)(Xn + t * 256 + (cg * 4 + i) * 8);
    } else {
#pragma unroll
      for (int i = 0; i < 4; ++i)
        *(u16x8*)(&Xp[p * XP_STR + (cg * 4 + i) * 8]) = (u16x8){0,0,0,0,0,0,0,0};
    }
  }
  for (int i = tid; i < 8 * 169; i += 512) relLh[i] = relL2[i];
  {
    const int h = tid >> 6, q = tid & 63;
    int qq = (q < 49) ? q : 48;
    int t = tmap(qq, gi, gj);
    aqsL[h * 64 + q] = b2f(Mn[(size_t)t * MSTR + 2048 + h]);
    bpsL[h * 64 + q] = b2f(Mn[(size_t)t * MSTR + 2056 + h]);
  }
  __syncthreads();

  bf16x8 xfr[4][2];
#pragma unroll
  for (int dt = 0; dt < 4; ++dt) {
    const int d = (wv * 4 + dt) * 16 + l16;
#pragma unroll
    for (int kk = 0; kk < 2; ++kk)
#pragma unroll
      for (int j = 0; j < 8; ++j)
        xfr[dt][kk][j] = (short)Xp[(kk * 32 + quad * 8 + j) * XP_STR + d];
  }

  const int q = wv * 16 + l16;
  const int qq = (q < 49) ? q : 48;
  const int tq = tmap(qq, gi, gj);
  const ushort_t* Mbase = Mn + (size_t)tq * MSTR + quad * 8;
  const int yq = div7(qq), xq = qq - yq * 7;
  const int fq = regof(gi * 7 + yq) * 3 + regof(gj * 7 + xq);

  for (int hh = 0; hh < 4; ++hh) {
    const int h = hh * 2 + group;
    f32x4 sacc[4];
#pragma unroll
    for (int pt = 0; pt < 4; ++pt) sacc[pt] = (f32x4){0.f, 0.f, 0.f, 0.f};
    const ushort_t* mrow = Mbase + h * 256;
#pragma unroll
    for (int kk = 0; kk < 8; ++kk) {
      bf16x8 bfm = *(const bf16x8*)(mrow + kk * 32);
#pragma unroll
      for (int pt = 0; pt < 4; ++pt) {
        bf16x8 af = *(const bf16x8*)(&Xp[(pt * 16 + l16) * XP_STR + kk * 32 + quad * 8]);
        sacc[pt] = __builtin_amdgcn_mfma_f32_16x16x32_bf16(af, bfm, sacc[pt], 0, 0, 0);
      }
    }
    float v[16];
    const float aqv = aqsL[h * 64 + q];
    const float* rel_h = &relLh[h * 169];
    float m = -1e30f;
#pragma unroll
    for (int pt = 0; pt < 4; ++pt)
#pragma unroll
      for (int r = 0; r < 4; ++r) {
        int p = pt * 16 + quad * 4 + r;
        float val = -1e30f;
        if (p < 49) {
          int yp = div7(p), xp = p - yp * 7;
          int fp = regof(gi * 7 + yp) * 3 + regof(gj * 7 + xp);
          val = (sacc[pt][r] + aqv + bpsL[h * 64 + p]) * 0.0625f +
                rel_h[(yp - yq + 6) + 13 * (xp - xq + 6)];
          if (fp != fq) val -= 100.f;
        }
        v[pt * 4 + r] = val;
        m = fmaxf(m, val);
      }
    m = fmaxf(m, __shfl_xor(m, 16));
    m = fmaxf(m, __shfl_xor(m, 32));
    float s = 0.f;
#pragma unroll
    for (int i = 0; i < 16; ++i) { v[i] = __expf(v[i] - m); s += v[i]; }
    s += __shfl_xor(s, 16);
    s += __shfl_xor(s, 32);
    const float inv = 1.f / s;
    __syncthreads();
    {
      ushort_t* sb = &StB[group][q * 72];
#pragma unroll
      for (int pt = 0; pt < 4; ++pt) {
        ushort4 u;
        u.x = f2b(v[pt * 4 + 0] * inv); u.y = f2b(v[pt * 4 + 1] * inv);
        u.z = f2b(v[pt * 4 + 2] * inv); u.w = f2b(v[pt * 4 + 3] * inv);
        *(ushort4*)(&sb[pt * 16 + quad * 4]) = u;
      }
    }
    __syncthreads();
#pragma unroll
    for (int qt = 0; qt < 4; ++qt) {
      f32x4 tacc[4];
#pragma unroll
      for (int dt = 0; dt < 4; ++dt) tacc[dt] = (f32x4){0.f, 0.f, 0.f, 0.f};
#pragma unroll
      for (int kk = 0; kk < 2; ++kk) {
        bf16x8 bfw = *(const bf16x8*)(&StB[group][(qt * 16 + l16) * 72 + kk * 32 + quad * 8]);
#pragma unroll
        for (int dt = 0; dt < 4; ++dt)
          tacc[dt] = __builtin_amdgcn_mfma_f32_16x16x32_bf16(xfr[dt][kk], bfw, tacc[dt], 0, 0, 0);
      }
      int q2 = qt * 16 + l16;
      if (q2 < 49) {
        int t2 = tmap(q2, gi, gj);
#pragma unroll
        for (int dt = 0; dt < 4; ++dt) {
          int d0 = (wv * 4 + dt) * 16 + quad * 4;
          *(ushort4*)(Mn + (size_t)t2 * MSTR + h * 256 + d0) = pack4(tacc[dt]);
        }
      }
    }
  }
}

// ================= gemm3: out[o][t] = Wov3 . T_T^T + cvec =================
// 128o x 128t tile, BK=128, 16 k-iters, DMA fills with XOR swizzle.
__global__ __launch_bounds__(256, 2) void k_gemm3(
    const ushort_t* __restrict__ Wov3, const ushort_t* __restrict__ MT,
    const float* __restrict__ cvec, float* __restrict__ out) {
  __shared__ ushort_t Asm[128 * 128];   // 32 KB
  __shared__ ushort_t Bsm[128 * 128];   // 32 KB
  const int bx0 = blockIdx.x;
  const int bx = (bx0 & 7) * 50 + (bx0 >> 3);    // bijective: 400 = 8*50
  const int n = bx / 50, r2 = bx % 50;
  const int oi = r2 / 25, tt = r2 % 25;
  const int o0 = oi * 128, t0 = tt * 128;
  const int tid = threadIdx.x, wave = tid >> 6, lane = tid & 63;
  const int quad = lane >> 4, l16 = lane & 15;
  const int wa = wave >> 1, wt = wave & 1;
  const ushort_t* Tn = MT + (size_t)n * TROWS * MSTR;
  float* on = out + (size_t)n * 256 * 3136;
  const int sw = l16 & 7;

  f32x4 acc[4][4];
#pragma unroll
  for (int i = 0; i < 4; ++i)
#pragma unroll
    for (int j = 0; j < 4; ++j) acc[i][j] = (f32x4){0.f, 0.f, 0.f, 0.f};

  for (int kit = 0; kit < 16; ++kit) {
    const int kb = kit * 128;
    // fill A[128][128] and B[128][128], 16B chunks, swizzle c^=(r&7)
#pragma unroll
    for (int i = 0; i < 8; ++i) {
      int S = i * 256 + tid;
      int rr = S >> 4, sc = S & 15;
      int c = (sc & 8) | ((sc ^ rr) & 7);
      gload_lds16(Wov3 + (o0 + rr) * 2048 + kb + c * 8,
                  &Asm[(i * 256 + wave * 64) * 8]);
    }
#pragma unroll
    for (int i = 0; i < 8; ++i) {
      int S = i * 256 + tid;
      int rr = S >> 4, sc = S & 15;
      int c = (sc & 8) | ((sc ^ rr) & 7);
      gload_lds16(Tn + (size_t)(t0 + rr) * MSTR + kb + c * 8,
                  &Bsm[(i * 256 + wave * 64) * 8]);
    }
    __syncthreads();
#pragma unroll
    for (int kk = 0; kk < 4; ++kk) {
      bf16x8 af[4], bf[4];
      const int c = kk * 4 + quad;
      const int pos = (c & 8) | ((c ^ sw) & 7);
#pragma unroll
      for (int i = 0; i < 4; ++i)
        af[i] = *(const bf16x8*)(&Asm[(wa * 64 + i * 16 + l16) * 128 + pos * 8]);
#pragma unroll
      for (int j = 0; j < 4; ++j)
        bf[j] = *(const bf16x8*)(&Bsm[(wt * 64 + j * 16 + l16) * 128 + pos * 8]);
#pragma unroll
      for (int i = 0; i < 4; ++i)
#pragma unroll
        for (int j = 0; j < 4; ++j)
          acc[i][j] = __builtin_amdgcn_mfma_f32_16x16x32_bf16(af[i], bf[j], acc[i][j], 0, 0, 0);
    }
    __syncthreads();
  }
  // epilogue: + cvec, guard pad tokens
#pragma unroll
  for (int i = 0; i < 4; ++i) {
    const int ob = o0 + wa * 64 + i * 16 + quad * 4;
    const float4 cv = *(const float4*)(cvec + ob);
#pragma unroll
    for (int j = 0; j < 4; ++j) {
      const int tg = t0 + wt * 64 + j * 16 + l16;
      if (tg < 3136) {
        on[(size_t)(ob + 0) * 3136 + tg] = acc[i][j][0] + cv.x;
        on[(size_t)(ob + 1) * 3136 + tg] = acc[i][j][1] + cv.y;
        on[(size_t)(ob + 2) * 3136 + tg] = acc[i][j][2] + cv.z;
        on[(size_t)(ob + 3) * 3136 + tg] = acc[i][j][3] + cv.w;
      }
    }
  }
}

extern "C" void kernel_launch(void* const* d_in, const int* in_sizes, int n_in,
                              void* d_out, int out_size, void* d_ws, size_t ws_size,
                              hipStream_t stream) {
  (void)in_sizes; (void)n_in; (void)out_size; (void)ws_size;
  const float* X  = (const float*)d_in[0];
  const float* Wk = (const float*)d_in[1];
  const float* bk = (const float*)d_in[2];
  const float* Wq = (const float*)d_in[3];
  const float* bq = (const float*)d_in[4];
  const float* Wv = (const float*)d_in[5];
  const float* bv = (const float*)d_in[6];
  const float* Wo = (const float*)d_in[7];
  const float* bo = (const float*)d_in[8];
  const float* rc = (const float*)d_in[9];

  ushort_t* MT    = (ushort_t*)d_ws;                       // 8*3200*2176 u16
  ushort_t* Xroll = MT + (size_t)8 * TROWS * MSTR;         // 8*3200*256 u16
  ushort_t* Aext  = Xroll + (size_t)8 * TROWS * 256;       // 2176*256 u16
  ushort_t* Wov3  = Aext + 2176 * 256;                     // 256*2048 u16
  float* fbase = (float*)(Wov3 + 256 * 2048);
  float* cvec  = fbase;         // 256 f32
  float* relL2 = fbase + 256;   // 8*169 f32
  float* out = (float*)d_out;

  k_prep <<<dim3(1290), dim3(256), 0, stream>>>(Wk, Wq, Wo, Wv, bk, bq, bv, bo, rc,
                                                Aext, Wov3, cvec, relL2);
  k_conv <<<dim3(8 * 57), dim3(256), 0, stream>>>(X, Xroll);
  k_gemm1<<<dim3(8 * 119), dim3(256), 0, stream>>>(Xroll, Aext, MT);
  k_attn2<<<dim3(8 * 64), dim3(512), 0, stream>>>(Xroll, MT, relL2);
  k_gemm3<<<dim3(8 * 50), dim3(256), 0, stream>>>(Wov3, MT, cvec, out);
}

// Round 10
// 288.679 us; speedup vs baseline: 1.5065x; 1.0166x over previous
//
#include <hip/hip_runtime.h>
#include <hip/hip_bf16.h>

// Swin window MHSA, MI355X, round 16.
//   Pipeline = R9 (session best, 274us): prep / conv(R9 original) / gemm1 /
//   attn2 / gemm3.
//   R16 changes:
//   (a) conv reverted to R9 version (R15's LDS-transpose conv was -19us:
//       old conv's scattered loads are L1-absorbed across x-iterations).
//   (b) gemm1 stores: per-wave LDS staging transpose. Old: ushort4 (8B)
//       per lane scattered over 64 lines/inst => 512 L2 line-requests per
//       wave-tile (8x inflated) ~= the 60us. New: stage C-frags a-major in
//       2KB/wave LDS (pad 66, ~2-way => free; per-wave private, NO barrier,
//       LDS ops in-order per wave), read t-major, store 16B/lane =
//       4 insts/wave x 8 FULL 128B lines. vmcnt counts: stores=4 => 12/4.

#define NBATCH 8
#define MSTR   2176           // M_T / T_T row stride (a'-dim, 17 tiles of 128)
#define TROWS  3200           // padded token rows (50 tiles of 64)

typedef unsigned short ushort_t;
typedef __attribute__((ext_vector_type(8))) short bf16x8;   // 8 bf16 = 4 VGPR
typedef __attribute__((ext_vector_type(8))) unsigned short u16x8;
typedef __attribute__((ext_vector_type(4))) float f32x4;    // MFMA acc

__device__ __forceinline__ float b2f(ushort_t u) {
  union { unsigned int i; float f; } v; v.i = ((unsigned int)u) << 16; return v.f;
}
__device__ __forceinline__ ushort_t f2b(float f) {
  union { float f; unsigned int u; } v; v.f = f;
  unsigned int u = v.u;
  return (ushort_t)((u + 0x7FFFu + ((u >> 16) & 1u)) >> 16);
}
__device__ __forceinline__ int regof(int y) { return (y < 49) ? 0 : ((y < 53) ? 1 : 2); }
__device__ __forceinline__ int div7(int t) { return (t * 37) >> 8; }  // t/7, t<64
__device__ __forceinline__ int tmap(int p, int gi, int gj) {
  int wi = div7(p); return (gi * 7 + wi) * 56 + gj * 7 + (p - wi * 7);
}
__device__ __forceinline__ ushort4 pack4(f32x4 a) {
  ushort4 u; u.x = f2b(a[0]); u.y = f2b(a[1]); u.z = f2b(a[2]); u.w = f2b(a[3]);
  return u;
}
// async global->LDS, 16B per lane; lds dest must be wave-uniform base
__device__ __forceinline__ void gload_lds16(const ushort_t* g, ushort_t* l) {
  __builtin_amdgcn_global_load_lds(
      (const __attribute__((address_space(1))) void*)g,
      (__attribute__((address_space(3))) void*)l, 16, 0, 0);
}
__device__ __forceinline__ void sb0() { __builtin_amdgcn_sched_barrier(0); }

// ================= prep (unchanged) =================
__global__ void k_prep(const float* __restrict__ Wk, const float* __restrict__ Wq,
                       const float* __restrict__ Wo, const float* __restrict__ Wv,
                       const float* __restrict__ bk, const float* __restrict__ bq,
                       const float* __restrict__ bv, const float* __restrict__ bo,
                       const float* __restrict__ relc,
                       ushort_t* __restrict__ Aext, ushort_t* __restrict__ Wov3,
                       float* __restrict__ cvec, float* __restrict__ relL2) {
  __shared__ float red[8];
  int blk = blockIdx.x, t = threadIdx.x;
  if (blk < 512) {
    int h = blk >> 6, b0 = (blk & 63) << 2, a = t;
    const float* wkh = Wk + h * 65536;
    const float* wqh = Wq + h * 65536;
    float a0 = 0.f, a1 = 0.f, a2 = 0.f, a3 = 0.f;
    for (int dd = 0; dd < 256; ++dd) {
      float wk = wkh[dd * 256 + a];
      float4 w4 = *(const float4*)(wqh + dd * 256 + b0);
      a0 += wk * w4.x; a1 += wk * w4.y; a2 += wk * w4.z; a3 += wk * w4.w;
    }
    ushort4 u; u.x = f2b(a0); u.y = f2b(a1); u.z = f2b(a2); u.w = f2b(a3);
    *(ushort4*)(Aext + (h * 256 + a) * 256 + b0) = u;
  } else if (blk < 1024) {
    int bb = blk - 512;
    int h = bb >> 6, o0 = (bb & 63) << 2, d = t;
    float a0 = 0.f, a1 = 0.f, a2 = 0.f, a3 = 0.f;
    for (int dd = 0; dd < 256; ++dd) {
      float wv = Wv[(h * 256 + dd) * 256 + d];
      a0 += Wo[(o0 + 0) * 2048 + h * 256 + dd] * wv;
      a1 += Wo[(o0 + 1) * 2048 + h * 256 + dd] * wv;
      a2 += Wo[(o0 + 2) * 2048 + h * 256 + dd] * wv;
      a3 += Wo[(o0 + 3) * 2048 + h * 256 + dd] * wv;
    }
    Wov3[(o0 + 0) * 2048 + h * 256 + d] = f2b(a0);
    Wov3[(o0 + 1) * 2048 + h * 256 + d] = f2b(a1);
    Wov3[(o0 + 2) * 2048 + h * 256 + d] = f2b(a2);
    Wov3[(o0 + 3) * 2048 + h * 256 + d] = f2b(a3);
  } else if (blk < 1032) {
    int h = blk - 1024;
    float s1 = 0.f, s2 = 0.f;
    for (int dd = 0; dd < 256; ++dd) {
      s1 += bk[h * 256 + dd] * Wq[(h * 256 + dd) * 256 + t];
      s2 += bq[h * 256 + dd] * Wk[(h * 256 + dd) * 256 + t];
    }
    Aext[(2048 + h) * 256 + t] = f2b(s1);
    Aext[(2056 + h) * 256 + t] = f2b(s2);
  } else if (blk == 1032) {
    for (int i = t; i < 112 * 256 / 8; i += 256)
      *(u16x8*)(Aext + 2064 * 256 + i * 8) = (u16x8){0,0,0,0,0,0,0,0};
  } else if (blk < 1289) {
    int o = blk - 1033;
    const float* wob = Wo + o * 2048;
    float acc = 0.f;
#pragma unroll
    for (int j = 0; j < 8; ++j) acc += wob[j * 256 + t] * bv[j * 256 + t];
#pragma unroll
    for (int s = 1; s < 64; s <<= 1) acc += __shfl_xor(acc, s);
    if ((t & 63) == 0) red[t >> 6] = acc;
    __syncthreads();
    if (t == 0) cvec[o] = bo[o] + red[0] + red[1] + red[2] + red[3];
  } else {
    if (t < 8) {
      float c = 0.f;
      for (int dd = 0; dd < 256; ++dd) c += bk[t * 256 + dd] * bq[t * 256 + dd];
      red[t] = c * 0.0625f;
    }
    __syncthreads();
    for (int i = t; i < 8 * 169; i += 256) {
      int h = i / 169, idx = i - h * 169;
      relL2[i] = relc[idx * 8 + h] + red[h];
    }
  }
}

// ================= conv: R9 original (scattered loads are L1-absorbed) ====
__global__ void k_conv(const float* __restrict__ X, ushort_t* __restrict__ Xroll) {
  const int n = blockIdx.x / 57, y = blockIdx.x % 57;
  ushort_t* xr = Xroll + (size_t)n * TROWS * 256;
  const int d = threadIdx.x;
  if (y == 56) {  // zero pad rows 3136..3199
    for (int i = d; i < 64 * 256 / 8; i += 256)
      *(u16x8*)(xr + 3136 * 256 + i * 8) = (u16x8){0,0,0,0,0,0,0,0};
    return;
  }
  const int c = d >> 4, p1 = (d >> 2) & 3, p2 = d & 3;
  const int sp = c * 16 + (((p1 + 1) & 3) << 2) + ((p2 + 1) & 3);
  const int ty = (p1 == 3) ? y : ((y == 0) ? 55 : y - 1);
  const float* rowp = X + (size_t)n * 256 * 3136 + sp * 3136 + ty * 56;
  ushort_t* orow = xr + y * 56 * 256 + d;
  for (int x = 0; x < 56; ++x) {
    int tx = (p2 == 3) ? x : ((x == 0) ? 55 : x - 1);
    orow[x * 256] = f2b(rowp[tx]);   // 256 lanes -> 512B contiguous store
  }
}

// ================= gemm1: M_T[t][a'] = Xroll . Aext^T =====================
// R9 persistent pipelined version + R16 staged stores.
__global__ __launch_bounds__(256, 2) void k_gemm1(
    const ushort_t* __restrict__ Xroll, const ushort_t* __restrict__ Aext,
    ushort_t* __restrict__ MT) {
  __shared__ ushort_t Bsm[2][64 * 256];   // 2 x 32 KB
  __shared__ ushort_t stg[4][16 * 66];    // per-wave store staging (2.1KB ea)
  const int bx0 = blockIdx.x;
  const int n = bx0 & 7;                  // XCD-bijective: XCD k owns batch k
  const int inner = bx0 >> 3;             // 0..118
  const int aa = inner % 17;
  const int c  = inner / 17;              // chunk 0..6
  const int a0 = aa * 128;
  const int tstart = (c == 0) ? 0 : (7 * c + 1);  // in 64-row tiles
  const int T = (c == 0) ? 8 : 7;                 // 8 + 6x7 = 50 tiles
  const int tid = threadIdx.x, wave = tid >> 6, lane = tid & 63;
  const int quad = lane >> 4, l16 = lane & 15;
  const int wa = wave >> 1, wt = wave & 1;
  const ushort_t* Xn = Xroll + (size_t)n * TROWS * 256;
  ushort_t* Mn = MT + (size_t)n * TROWS * MSTR;

  // ---- A-slice into regs: wave owns rows [a0+wa*64, +64), full K ----
  const ushort_t* abase = Aext + (size_t)(a0 + wa * 64 + l16) * 256 + quad * 8;
  bf16x8 areg[8][4];
#pragma unroll
  for (int kk = 0; kk < 8; ++kk)
#pragma unroll
    for (int i = 0; i < 4; ++i)
      areg[kk][i] = *(const bf16x8*)(abase + i * 4096 + kk * 32);   // 32 loads
  sb0();

  // ---- DMA fill of one 64x256 tile (swizzled), 8 insts/wave ----
  auto fill = [&](int mt, int b) {
    const ushort_t* src = Xn + (size_t)(tstart + mt) * 64 * 256;
#pragma unroll
    for (int i = 0; i < 8; ++i) {
      int S = i * 256 + tid;
      int rr = S >> 5, sc = S & 31;
      int cc = (sc & 24) | ((sc ^ rr) & 7);
      gload_lds16(src + rr * 256 + cc * 8, &Bsm[b][(i * 256 + wave * 64) * 8]);
    }
  };

  fill(0, 0); sb0();
  fill(1, 1); sb0();
  // outstanding: A(32), f0(8), f1(8). vmcnt(8) => A + f0 complete.
  asm volatile("s_waitcnt vmcnt(8)" ::: "memory"); sb0();
  __builtin_amdgcn_s_barrier(); sb0();

  const int sw = l16 & 7;
  ushort_t* stp = stg[wave];
  const int rd_t = lane >> 3;        // staging read: 8 rows/inst
  const int rd_a = (lane & 7) * 8;   // 8 a-values = 16B/lane
  for (int m = 0; m < T; ++m) {
    if (m > 0) {
      // need fill(m) done. Issued after it: stores(m-1)[4] (+ fill(m+1)[8]).
      if (m + 1 < T) { asm volatile("s_waitcnt vmcnt(12)" ::: "memory"); }
      else           { asm volatile("s_waitcnt vmcnt(4)"  ::: "memory"); }
      sb0();
      __builtin_amdgcn_s_barrier(); sb0();
    }
    const int b = m & 1;
    f32x4 acc[4][2];
#pragma unroll
    for (int i = 0; i < 4; ++i)
#pragma unroll
      for (int j = 0; j < 2; ++j) acc[i][j] = (f32x4){0.f, 0.f, 0.f, 0.f};
#pragma unroll
    for (int kk = 0; kk < 8; ++kk) {
      bf16x8 bfj[2];
#pragma unroll
      for (int j = 0; j < 2; ++j) {
        int rr = wt * 32 + j * 16 + l16;
        int cc = kk * 4 + quad;
        int pos = (cc & 24) | ((cc ^ sw) & 7);
        bfj[j] = *(const bf16x8*)(&Bsm[b][rr * 256 + pos * 8]);
      }
#pragma unroll
      for (int i = 0; i < 4; ++i)
#pragma unroll
        for (int j = 0; j < 2; ++j)
          acc[i][j] = __builtin_amdgcn_mfma_f32_16x16x32_bf16(areg[kk][i], bfj[j], acc[i][j], 0, 0, 0);
    }
    // ---- staged stores: 4 full-line insts/wave (was 8 x 64-line scatter) --
    const int tb = (tstart + m) * 64;
#pragma unroll
    for (int j = 0; j < 2; ++j) {
      // stage a-major: row = t-local (l16), col = a-local (pad-66 stride)
#pragma unroll
      for (int i = 0; i < 4; ++i)
        *(ushort4*)(&stp[l16 * 66 + i * 16 + quad * 4]) = pack4(acc[i][j]);
      // per-wave private; LDS ops in-order per wave -> no barrier needed
#pragma unroll
      for (int it = 0; it < 2; ++it) {
        const int tl = it * 8 + rd_t;
        bf16x8 vv = *(const bf16x8*)(&stp[tl * 66 + rd_a]);
        *(bf16x8*)(Mn + (size_t)(tb + wt * 32 + j * 16 + tl) * MSTR +
                   a0 + wa * 64 + rd_a) = vv;   // 8 lanes/line: full lines
      }
      if (j == 0) { asm volatile("s_waitcnt lgkmcnt(0)" ::: "memory"); sb0(); }
    }
    sb0();
    __builtin_amdgcn_s_barrier(); sb0();   // all waves done reading buf b
    if (m + 2 < T) { fill(m + 2, b); sb0(); }
  }
}

// ================= attn2 (unchanged) ==============================
#define XP_STR 264
__global__ __launch_bounds__(512, 4) void k_attn2(
    const ushort_t* __restrict__ Xroll, ushort_t* __restrict__ MT,
    const float* __restrict__ relL2) {
  __shared__ ushort_t Xp[64 * XP_STR];
  __shared__ ushort_t StB[2][64 * 72];
  __shared__ float aqsL[8 * 64];
  __shared__ float bpsL[8 * 64];
  __shared__ float relLh[8 * 169];

  const int tid = threadIdx.x;
  const int wave = tid >> 6, lane = tid & 63;
  const int quad = lane >> 4, l16 = lane & 15;
  const int group = wave >> 2, wv = wave & 3;
  const int n = blockIdx.x >> 6, g = blockIdx.x & 63;
  const int gi = g >> 3, gj = g & 7;
  const ushort_t* Xn = Xroll + (size_t)n * TROWS * 256;
  ushort_t* Mn = MT + (size_t)n * TROWS * MSTR;

  {
    const int p = tid & 63, cg = tid >> 6;
    if (p < 49) {
      int t = tmap(p, gi, gj);
#pragma unroll
      for (int i = 0; i < 4; ++i)
        *(u16x8*)(&Xp[p * XP_STR + (cg * 4 + i) * 8]) =
            *(const u16x8*)(Xn + t * 256 + (cg * 4 + i) * 8);
    } else {
#pragma unroll
      for (int i = 0; i < 4; ++i)
        *(u16x8*)(&Xp[p * XP_STR + (cg * 4 + i) * 8]) = (u16x8){0,0,0,0,0,0,0,0};
    }
  }
  for (int i = tid; i < 8 * 169; i += 512) relLh[i] = relL2[i];
  {
    const int h = tid >> 6, q = tid & 63;
    int qq = (q < 49) ? q : 48;
    int t = tmap(qq, gi, gj);
    aqsL[h * 64 + q] = b2f(Mn[(size_t)t * MSTR + 2048 + h]);
    bpsL[h * 64 + q] = b2f(Mn[(size_t)t * MSTR + 2056 + h]);
  }
  __syncthreads();

  bf16x8 xfr[4][2];
#pragma unroll
  for (int dt = 0; dt < 4; ++dt) {
    const int d = (wv * 4 + dt) * 16 + l16;
#pragma unroll
    for (int kk = 0; kk < 2; ++kk)
#pragma unroll
      for (int j = 0; j < 8; ++j)
        xfr[dt][kk][j] = (short)Xp[(kk * 32 + quad * 8 + j) * XP_STR + d];
  }

  const int q = wv * 16 + l16;
  const int qq = (q < 49) ? q : 48;
  const int tq = tmap(qq, gi, gj);
  const ushort_t* Mbase = Mn + (size_t)tq * MSTR + quad * 8;
  const int yq = div7(qq), xq = qq - yq * 7;
  const int fq = regof(gi * 7 + yq) * 3 + regof(gj * 7 + xq);

  for (int hh = 0; hh < 4; ++hh) {
    const int h = hh * 2 + group;
    f32x4 sacc[4];
#pragma unroll
    for (int pt = 0; pt < 4; ++pt) sacc[pt] = (f32x4){0.f, 0.f, 0.f, 0.f};
    const ushort_t* mrow = Mbase + h * 256;
#pragma unroll
    for (int kk = 0; kk < 8; ++kk) {
      bf16x8 bfm = *(const bf16x8*)(mrow + kk * 32);
#pragma unroll
      for (int pt = 0; pt < 4; ++pt) {
        bf16x8 af = *(const bf16x8*)(&Xp[(pt * 16 + l16) * XP_STR + kk * 32 + quad * 8]);
        sacc[pt] = __builtin_amdgcn_mfma_f32_16x16x32_bf16(af, bfm, sacc[pt], 0, 0, 0);
      }
    }
    float v[16];
    const float aqv = aqsL[h * 64 + q];
    const float* rel_h = &relLh[h * 169];
    float m = -1e30f;
#pragma unroll
    for (int pt = 0; pt < 4; ++pt)
#pragma unroll
      for (int r = 0; r < 4; ++r) {
        int p = pt * 16 + quad * 4 + r;
        float val = -1e30f;
        if (p < 49) {
          int yp = div7(p), xp = p - yp * 7;
          int fp = regof(gi * 7 + yp) * 3 + regof(gj * 7 + xp);
          val = (sacc[pt][r] + aqv + bpsL[h * 64 + p]) * 0.0625f +
                rel_h[(yp - yq + 6) + 13 * (xp - xq + 6)];
          if (fp != fq) val -= 100.f;
        }
        v[pt * 4 + r] = val;
        m = fmaxf(m, val);
      }
    m = fmaxf(m, __shfl_xor(m, 16));
    m = fmaxf(m, __shfl_xor(m, 32));
    float s = 0.f;
#pragma unroll
    for (int i = 0; i < 16; ++i) { v[i] = __expf(v[i] - m); s += v[i]; }
    s += __shfl_xor(s, 16);
    s += __shfl_xor(s, 32);
    const float inv = 1.f / s;
    __syncthreads();
    {
      ushort_t* sb = &StB[group][q * 72];
#pragma unroll
      for (int pt = 0; pt < 4; ++pt) {
        ushort4 u;
        u.x = f2b(v[pt * 4 + 0] * inv); u.y = f2b(v[pt * 4 + 1] * inv);
        u.z = f2b(v[pt * 4 + 2] * inv); u.w = f2b(v[pt * 4 + 3] * inv);
        *(ushort4*)(&sb[pt * 16 + quad * 4]) = u;
      }
    }
    __syncthreads();
#pragma unroll
    for (int qt = 0; qt < 4; ++qt) {
      f32x4 tacc[4];
#pragma unroll
      for (int dt = 0; dt < 4; ++dt) tacc[dt] = (f32x4){0.f, 0.f, 0.f, 0.f};
#pragma unroll
      for (int kk = 0; kk < 2; ++kk) {
        bf16x8 bfw = *(const bf16x8*)(&StB[group][(qt * 16 + l16) * 72 + kk * 32 + quad * 8]);
#pragma unroll
        for (int dt = 0; dt < 4; ++dt)
          tacc[dt] = __builtin_amdgcn_mfma_f32_16x16x32_bf16(xfr[dt][kk], bfw, tacc[dt], 0, 0, 0);
      }
      int q2 = qt * 16 + l16;
      if (q2 < 49) {
        int t2 = tmap(q2, gi, gj);
#pragma unroll
        for (int dt = 0; dt < 4; ++dt) {
          int d0 = (wv * 4 + dt) * 16 + quad * 4;
          *(ushort4*)(Mn + (size_t)t2 * MSTR + h * 256 + d0) = pack4(tacc[dt]);
        }
      }
    }
  }
}

// ================= gemm3: out[o][t] = Wov3 . T_T^T + cvec =================
// 128o x 128t tile, BK=128, 16 k-iters, DMA fills with XOR swizzle.
__global__ __launch_bounds__(256, 2) void k_gemm3(
    const ushort_t* __restrict__ Wov3, const ushort_t* __restrict__ MT,
    const float* __restrict__ cvec, float* __restrict__ out) {
  __shared__ ushort_t Asm[128 * 128];   // 32 KB
  __shared__ ushort_t Bsm[128 * 128];   // 32 KB
  const int bx0 = blockIdx.x;
  const int bx = (bx0 & 7) * 50 + (bx0 >> 3);    // bijective: 400 = 8*50
  const int n = bx / 50, r2 = bx % 50;
  const int oi = r2 / 25, tt = r2 % 25;
  const int o0 = oi * 128, t0 = tt * 128;
  const int tid = threadIdx.x, wave = tid >> 6, lane = tid & 63;
  const int quad = lane >> 4, l16 = lane & 15;
  const int wa = wave >> 1, wt = wave & 1;
  const ushort_t* Tn = MT + (size_t)n * TROWS * MSTR;
  float* on = out + (size_t)n * 256 * 3136;
  const int sw = l16 & 7;

  f32x4 acc[4][4];
#pragma unroll
  for (int i = 0; i < 4; ++i)
#pragma unroll
    for (int j = 0; j < 4; ++j) acc[i][j] = (f32x4){0.f, 0.f, 0.f, 0.f};

  for (int kit = 0; kit < 16; ++kit) {
    const int kb = kit * 128;
    // fill A[128][128] and B[128][128], 16B chunks, swizzle c^=(r&7)
#pragma unroll
    for (int i = 0; i < 8; ++i) {
      int S = i * 256 + tid;
      int rr = S >> 4, sc = S & 15;
      int c = (sc & 8) | ((sc ^ rr) & 7);
      gload_lds16(Wov3 + (o0 + rr) * 2048 + kb + c * 8,
                  &Asm[(i * 256 + wave * 64) * 8]);
    }
#pragma unroll
    for (int i = 0; i < 8; ++i) {
      int S = i * 256 + tid;
      int rr = S >> 4, sc = S & 15;
      int c = (sc & 8) | ((sc ^ rr) & 7);
      gload_lds16(Tn + (size_t)(t0 + rr) * MSTR + kb + c * 8,
                  &Bsm[(i * 256 + wave * 64) * 8]);
    }
    __syncthreads();
#pragma unroll
    for (int kk = 0; kk < 4; ++kk) {
      bf16x8 af[4], bf[4];
      const int c = kk * 4 + quad;
      const int pos = (c & 8) | ((c ^ sw) & 7);
#pragma unroll
      for (int i = 0; i < 4; ++i)
        af[i] = *(const bf16x8*)(&Asm[(wa * 64 + i * 16 + l16) * 128 + pos * 8]);
#pragma unroll
      for (int j = 0; j < 4; ++j)
        bf[j] = *(const bf16x8*)(&Bsm[(wt * 64 + j * 16 + l16) * 128 + pos * 8]);
#pragma unroll
      for (int i = 0; i < 4; ++i)
#pragma unroll
        for (int j = 0; j < 4; ++j)
          acc[i][j] = __builtin_amdgcn_mfma_f32_16x16x32_bf16(af[i], bf[j], acc[i][j], 0, 0, 0);
    }
    __syncthreads();
  }
  // epilogue: + cvec, guard pad tokens
#pragma unroll
  for (int i = 0; i < 4; ++i) {
    const int ob = o0 + wa * 64 + i * 16 + quad * 4;
    const float4 cv = *(const float4*)(cvec + ob);
#pragma unroll
    for (int j = 0; j < 4; ++j) {
      const int tg = t0 + wt * 64 + j * 16 + l16;
      if (tg < 3136) {
        on[(size_t)(ob + 0) * 3136 + tg] = acc[i][j][0] + cv.x;
        on[(size_t)(ob + 1) * 3136 + tg] = acc[i][j][1] + cv.y;
        on[(size_t)(ob + 2) * 3136 + tg] = acc[i][j][2] + cv.z;
        on[(size_t)(ob + 3) * 3136 + tg] = acc[i][j][3] + cv.w;
      }
    }
  }
}

extern "C" void kernel_launch(void* const* d_in, const int* in_sizes, int n_in,
                              void* d_out, int out_size, void* d_ws, size_t ws_size,
                              hipStream_t stream) {
  (void)in_sizes; (void)n_in; (void)out_size; (void)ws_size;
  const float* X  = (const float*)d_in[0];
  const float* Wk = (const float*)d_in[1];
  const float* bk = (const float*)d_in[2];
  const float* Wq = (const float*)d_in[3];
  const float* bq = (const float*)d_in[4];
  const float* Wv = (const float*)d_in[5];
  const float* bv = (const float*)d_in[6];
  const float* Wo = (const float*)d_in[7];
  const float* bo = (const float*)d_in[8];
  const float* rc = (const float*)d_in[9];

  ushort_t* MT    = (ushort_t*)d_ws;                       // 8*3200*2176 u16
  ushort_t* Xroll = MT + (size_t)8 * TROWS * MSTR;         // 8*3200*256 u16
  ushort_t* Aext  = Xroll + (size_t)8 * TROWS * 256;       // 2176*256 u16
  ushort_t* Wov3  = Aext + 2176 * 256;                     // 256*2048 u16
  float* fbase = (float*)(Wov3 + 256 * 2048);
  float* cvec  = fbase;         // 256 f32
  float* relL2 = fbase + 256;   // 8*169 f32
  float* out = (float*)d_out;

  k_prep <<<dim3(1290), dim3(256), 0, stream>>>(Wk, Wq, Wo, Wv, bk, bq, bv, bo, rc,
                                                Aext, Wov3, cvec, relL2);
  k_conv <<<dim3(8 * 57), dim3(256), 0, stream>>>(X, Xroll);
  k_gemm1<<<dim3(8 * 119), dim3(256), 0, stream>>>(Xroll, Aext, MT);
  k_attn2<<<dim3(8 * 64), dim3(512), 0, stream>>>(Xroll, MT, relL2);
  k_gemm3<<<dim3(8 * 50), dim3(256), 0, stream>>>(Wov3, MT, cvec, out);
}